// Round 7
// baseline (892.763 us; speedup 1.0000x reference)
//
#include <hip/hip_runtime.h>
#include <hip/hip_bf16.h>

#define N_NODES 500000
#define E_EDGES 500000
#define FDIM 128
#define BN_EPS 1e-3f
#define OFFS 500001  // per-side stride of the offsets array
#define GCAP 128    // edges staged per chunk in gather

// ws layout (in floats):
//   [0, 16384)        buckets: 64 x (sum[128], sumsq[128])
//   [16384, 16640)    scaleshift: scale[128], shift[128]
//   [16640, 65792)    pw  (gru weights)  bf16 fragment-order, 192 KB
//   [65792, 82176)    pw2 (aggre weights) bf16 fragment-order, 64 KB
//   [82176, ...)      prev_bf [N][128] bf16 (128 MB), then next_bf [N][128] bf16
//   a_bf ALIASES prev_bf (aggre reads its rows to LDS before overwriting them).
#define WS_BUCKETS 0
#define WS_SCALESHIFT 16384
#define WS_PW 16640
#define WS_PW2 65792
#define WS_PREV 82176

// d_out u32 scratch layout (dead once gru_mfma writes d_out at the very end):
//   CNT  at 0         : u32[2][500000]
//   OFF  at 1000000   : u32[2][500001]
//   PART at 2100000   : u32[2][512]
//   CUR  at 2200000   : u32[2][500000]
//   SRC  at 3200000   : u32[2][500000]   (ends at 16.8 MB)
//   XBF  at 6000000   : bf16[N][128]     (24 MB .. 152 MB; read by gather+aggre only)
#define SO_CNT 0
#define SO_OFF 1000000
#define SO_PART 2100000
#define SO_CUR 2200000
#define SO_SRC 3200000
#define SO_XBF 6000000

typedef __attribute__((ext_vector_type(4))) float v4f;
typedef __attribute__((ext_vector_type(8))) __bf16 v8bf;

__device__ __forceinline__ unsigned f2bf_u(float f) {
  unsigned u = __float_as_uint(f);
  return ((u + 0x7FFF + ((u >> 16) & 1)) >> 16) & 0xFFFF;
}
__device__ __forceinline__ unsigned f2bf2(float a, float b) {
  return f2bf_u(a) | (f2bf_u(b) << 16);
}
__device__ __forceinline__ float bf2f(unsigned short u) {
  return __uint_as_float((unsigned)u << 16);
}
__device__ __forceinline__ float fast_sigmoid(float x) {
  float e = __expf(-x);
  return __builtin_amdgcn_rcpf(1.f + e);
}
__device__ __forceinline__ float fast_tanh(float x) {
  x = fminf(fmaxf(x, -15.f), 15.f);
  float e = __expf(2.f * x);
  return (e - 1.f) * __builtin_amdgcn_rcpf(e + 1.f);
}

// ---------------------------------------------------------------- weight repack
__global__ __launch_bounds__(256) void repack_gru(
    const float* __restrict__ gk, const float* __restrict__ rk,
    unsigned short* __restrict__ pw) {
  int idx = blockIdx.x * 256 + threadIdx.x;  // 0..98303
  int side = idx / 49152;
  int rem = idx % 49152;
  int gate = rem >> 14;
  int rr = rem & 16383;
  int c = rr >> 7, k = rr & 127;
  const float* src = side ? rk : gk;
  float v = src[k * 384 + gate * 128 + c];
  int w = c >> 5, nb = (c >> 4) & 1, l15 = c & 15;
  int ks = k >> 5, lg = (k >> 3) & 3, j = k & 7;
  int lane = lg * 16 + l15;
  int e = w * 24576 + ks * 6144 + nb * 3072 + gate * 1024 + side * 512 + lane * 8 + j;
  pw[e] = (unsigned short)f2bf_u(v);
}

__global__ __launch_bounds__(256) void repack_w(
    const float* __restrict__ w_next, const float* __restrict__ w_prev,
    unsigned short* __restrict__ pw2) {
  int idx = blockIdx.x * 256 + threadIdx.x;  // 0..32767
  int side = idx >> 14;
  int rr = idx & 16383;
  int c = rr >> 7, k = rr & 127;
  const float* src = side ? w_prev : w_next;
  float v = src[k * 128 + c];
  int nh = c >> 6, nb = (c >> 4) & 3, l15 = c & 15;
  int ks = k >> 5, lg = (k >> 3) & 3, j = k & 7;
  int lane = lg * 16 + l15;
  int e = nh * 16384 + ks * 4096 + nb * 1024 + side * 512 + lane * 8 + j;
  pw2[e] = (unsigned short)f2bf_u(v);
}

// ---------------------------------------------------------------- x -> bf16
__global__ __launch_bounds__(256) void xbf_kernel(const float* __restrict__ x,
                                                  unsigned short* __restrict__ xbf) {
  size_t i = ((size_t)blockIdx.x * 256 + threadIdx.x) * 8;
  if (i >= (size_t)N_NODES * FDIM) return;
  float4 a = *(const float4*)(x + i);
  float4 b = *(const float4*)(x + i + 4);
  uint4 o = make_uint4(f2bf2(a.x, a.y), f2bf2(a.z, a.w), f2bf2(b.x, b.y),
                       f2bf2(b.z, b.w));
  *(uint4*)(xbf + i) = o;
}

// ---------------------------------------------------------------- CSR build
__global__ __launch_bounds__(256) void hist_kernel(const int* __restrict__ pp,
                                                   const int* __restrict__ pn,
                                                   unsigned* __restrict__ cnt) {
  int i = blockIdx.x * 256 + threadIdx.x;
  if (i >= 2 * E_EDGES) return;
  int side = i >= E_EDGES;
  const int* pair = side ? pn + 2 * (i - E_EDGES) : pp + 2 * i;
  atomicAdd(&cnt[side * N_NODES + pair[0]], 1u);
}

__global__ __launch_bounds__(256) void scan1_kernel(const unsigned* __restrict__ cnt,
                                                    unsigned* __restrict__ off,
                                                    unsigned* __restrict__ part) {
  __shared__ unsigned ls[256];
  int side = blockIdx.y;
  int b = blockIdx.x;
  int td = threadIdx.x;
  int base = b * 1024 + td * 4;
  const unsigned* c = cnt + (size_t)side * N_NODES;
  unsigned v0 = 0, v1 = 0, v2 = 0, v3 = 0;
  if (base + 3 < N_NODES) {
    v0 = c[base]; v1 = c[base + 1]; v2 = c[base + 2]; v3 = c[base + 3];
  } else {
    if (base < N_NODES) v0 = c[base];
    if (base + 1 < N_NODES) v1 = c[base + 1];
    if (base + 2 < N_NODES) v2 = c[base + 2];
  }
  unsigned s = v0 + v1 + v2 + v3;
  ls[td] = s;
  __syncthreads();
  unsigned run = s;
  for (int st = 1; st < 256; st <<= 1) {
    unsigned o = (td >= st) ? ls[td - st] : 0u;
    __syncthreads();
    run += o;
    ls[td] = run;
    __syncthreads();
  }
  unsigned excl = run - s;
  unsigned* oo = off + (size_t)side * OFFS;
  if (base < N_NODES) oo[base] = excl;
  if (base + 1 < N_NODES) oo[base + 1] = excl + v0;
  if (base + 2 < N_NODES) oo[base + 2] = excl + v0 + v1;
  if (base + 3 < N_NODES) oo[base + 3] = excl + v0 + v1 + v2;
  if (td == 255) part[side * 512 + b] = run;
}

__global__ __launch_bounds__(1024) void scan2_kernel(unsigned* __restrict__ part) {
  __shared__ unsigned ls[1024];
  int td = threadIdx.x;
  int b = td & 511;
  unsigned s = part[td];
  ls[td] = s;
  __syncthreads();
  unsigned run = s;
  for (int st = 1; st < 512; st <<= 1) {
    unsigned o = (b >= st) ? ls[td - st] : 0u;
    __syncthreads();
    run += o;
    ls[td] = run;
    __syncthreads();
  }
  part[td] = run - s;
}

__global__ __launch_bounds__(256) void scan3_kernel(unsigned* __restrict__ off,
                                                    const unsigned* __restrict__ part,
                                                    unsigned* __restrict__ cur) {
  int side = blockIdx.y;
  int i = blockIdx.x * 256 + threadIdx.x;
  if (i < N_NODES) {
    unsigned v = off[(size_t)side * OFFS + i] + part[side * 512 + (i >> 10)];
    off[(size_t)side * OFFS + i] = v;
    cur[(size_t)side * N_NODES + i] = v;
  }
  if (i == 0) off[(size_t)side * OFFS + N_NODES] = E_EDGES;
}

__global__ __launch_bounds__(256) void reorder_kernel(const int* __restrict__ pp,
                                                      const int* __restrict__ pn,
                                                      unsigned* __restrict__ cur,
                                                      unsigned* __restrict__ srcbuf) {
  int i = blockIdx.x * 256 + threadIdx.x;
  if (i >= 2 * E_EDGES) return;
  int side = i >= E_EDGES;
  const int* pair = side ? pn + 2 * (i - E_EDGES) : pp + 2 * i;
  unsigned pos = atomicAdd(&cur[(size_t)side * N_NODES + pair[0]], 1u);
  srcbuf[(size_t)side * E_EDGES + pos] = (unsigned)pair[1];
}

// ---------------------------------------------------------------- gather (segment sum)
__global__ __launch_bounds__(256) void gather_kernel(
    const unsigned short* __restrict__ xbf, const unsigned* __restrict__ off,
    const unsigned* __restrict__ srcbuf, unsigned short* __restrict__ prev_bf,
    unsigned short* __restrict__ next_bf) {
  __shared__ unsigned short stage[GCAP][128];  // 32 KB
  __shared__ unsigned soff[33];
  __shared__ unsigned ssrc[GCAP];
  int side = blockIdx.y;
  int r0 = blockIdx.x * 32;
  int t = threadIdx.x;
  const unsigned* oo = off + (size_t)side * OFFS + r0;
  if (t < 33) soff[t] = oo[t];
  __syncthreads();
  unsigned e0 = soff[0], e1 = soff[32];
  const unsigned* sl = srcbuf + (size_t)side * E_EDGES;

  float acc[16];
#pragma unroll
  for (int i = 0; i < 16; ++i) acc[i] = 0.f;
  int rr = t >> 3, fc = t & 7;  // my row, my 16-feature chunk

  for (unsigned base = e0; base < e1; base += GCAP) {
    unsigned cnt = min((unsigned)GCAP, e1 - base);
    if (t < cnt) ssrc[t] = sl[base + t];
    __syncthreads();
    int g = t >> 5, ld = t & 31;
    for (unsigned j = g; j < cnt; j += 8) {
      size_t s = ssrc[j];
      uint2 v = *(const uint2*)(xbf + s * FDIM + ld * 4);
      *(uint2*)&stage[j][ld * 4] = v;
    }
    __syncthreads();
    unsigned rs = soff[rr] > base ? soff[rr] : base;
    unsigned re = soff[rr + 1] < base + GCAP ? soff[rr + 1] : base + GCAP;
    for (unsigned i = rs; i < re; ++i) {
      uint4 u0 = *(const uint4*)&stage[i - base][fc * 16];
      uint4 u1 = *(const uint4*)&stage[i - base][fc * 16 + 8];
      acc[0] += bf2f((unsigned short)(u0.x & 0xffff)); acc[1] += __uint_as_float(u0.x & 0xffff0000u);
      acc[2] += bf2f((unsigned short)(u0.y & 0xffff)); acc[3] += __uint_as_float(u0.y & 0xffff0000u);
      acc[4] += bf2f((unsigned short)(u0.z & 0xffff)); acc[5] += __uint_as_float(u0.z & 0xffff0000u);
      acc[6] += bf2f((unsigned short)(u0.w & 0xffff)); acc[7] += __uint_as_float(u0.w & 0xffff0000u);
      acc[8] += bf2f((unsigned short)(u1.x & 0xffff)); acc[9] += __uint_as_float(u1.x & 0xffff0000u);
      acc[10] += bf2f((unsigned short)(u1.y & 0xffff)); acc[11] += __uint_as_float(u1.y & 0xffff0000u);
      acc[12] += bf2f((unsigned short)(u1.z & 0xffff)); acc[13] += __uint_as_float(u1.z & 0xffff0000u);
      acc[14] += bf2f((unsigned short)(u1.w & 0xffff)); acc[15] += __uint_as_float(u1.w & 0xffff0000u);
    }
    __syncthreads();
  }

  unsigned short* dst = (side ? next_bf : prev_bf) + (size_t)(r0 + rr) * FDIM + fc * 16;
  uint4 o0 = make_uint4(f2bf2(acc[0], acc[1]), f2bf2(acc[2], acc[3]),
                        f2bf2(acc[4], acc[5]), f2bf2(acc[6], acc[7]));
  uint4 o1 = make_uint4(f2bf2(acc[8], acc[9]), f2bf2(acc[10], acc[11]),
                        f2bf2(acc[12], acc[13]), f2bf2(acc[14], acc[15]));
  *(uint4*)dst = o0;
  *(uint4*)(dst + 8) = o1;
}

// ---------------------------------------------------------------- aggre (MFMA) + relu + BN-stats
__global__ __launch_bounds__(256) void aggre_mfma(
    const unsigned short* prev_bf, const unsigned short* __restrict__ next_bf,
    const unsigned short* __restrict__ xbf, const unsigned short* __restrict__ pw2,
    const float* __restrict__ b, unsigned short* a_out,
    float* __restrict__ buckets) {
  __shared__ unsigned short Ap[32 * 128];
  __shared__ unsigned short An[32 * 128];
  __shared__ float rs[2][128];
  __shared__ float rq[2][128];
  int t = threadIdx.x;
  int r0 = blockIdx.x * 32;

#pragma unroll
  for (int i = 0; i < 2; ++i) {
    int q = t + 256 * i;
    int row = q >> 4, kq = q & 15;
    size_t g = (size_t)(r0 + row) * FDIM + kq * 8;
    uint4 pv = *(const uint4*)(prev_bf + g);
    uint4 nv = *(const uint4*)(next_bf + g);
    int byte = (row * 256 + kq * 16) ^ ((row & 7) << 4);
    *(uint4*)((char*)Ap + byte) = pv;
    *(uint4*)((char*)An + byte) = nv;
  }
  __syncthreads();

  int w = t >> 6, lane = t & 63;
  int m0 = (w & 1) * 16, nh = w >> 1;
  int l15 = lane & 15, lg = lane >> 4;

  v4f acc[4];
#pragma unroll
  for (int nb = 0; nb < 4; ++nb) acc[nb] = (v4f){0.f, 0.f, 0.f, 0.f};

#pragma unroll
  for (int ks = 0; ks < 4; ++ks) {
    int mm = m0 + l15;
    int byte = (mm * 256 + ks * 64 + lg * 16) ^ ((mm & 7) << 4);
    v8bf ap = __builtin_bit_cast(v8bf, *(const uint4*)((const char*)Ap + byte));
    v8bf an = __builtin_bit_cast(v8bf, *(const uint4*)((const char*)An + byte));
    const unsigned short* wb = pw2 + nh * 16384 + ks * 4096 + lane * 8;
#pragma unroll
    for (int nb = 0; nb < 4; ++nb) {
      v8bf bn_ = __builtin_bit_cast(v8bf, *(const uint4*)(wb + nb * 1024));
      v8bf bp_ = __builtin_bit_cast(v8bf, *(const uint4*)(wb + nb * 1024 + 512));
      acc[nb] = __builtin_amdgcn_mfma_f32_16x16x32_bf16(an, bn_, acc[nb], 0, 0, 0);
      acc[nb] = __builtin_amdgcn_mfma_f32_16x16x32_bf16(ap, bp_, acc[nb], 0, 0, 0);
    }
  }

  float s1[4], s2[4];
#pragma unroll
  for (int nb = 0; nb < 4; ++nb) {
    int c = nh * 64 + nb * 16 + l15;
    float bb = b[c];
    s1[nb] = 0.f;
    s2[nb] = 0.f;
#pragma unroll
    for (int r = 0; r < 4; ++r) {
      int row = r0 + m0 + 4 * lg + r;
      size_t off = (size_t)row * FDIM + c;
      float v = acc[nb][r] + bb + bf2f(xbf[off]);
      v = fmaxf(v, 0.f);
      a_out[off] = (unsigned short)f2bf_u(v);
      s1[nb] += v;
      s2[nb] += v * v;
    }
    s1[nb] += __shfl_xor(s1[nb], 16);
    s1[nb] += __shfl_xor(s1[nb], 32);
    s2[nb] += __shfl_xor(s2[nb], 16);
    s2[nb] += __shfl_xor(s2[nb], 32);
  }
  if (lane < 16) {
#pragma unroll
    for (int nb = 0; nb < 4; ++nb) {
      rs[w & 1][nh * 64 + nb * 16 + lane] = s1[nb];
      rq[w & 1][nh * 64 + nb * 16 + lane] = s2[nb];
    }
  }
  __syncthreads();
  if (t < 128) {
    float s = rs[0][t] + rs[1][t];
    float q = rq[0][t] + rq[1][t];
    float* bkt = buckets + (size_t)(blockIdx.x & 63) * 256;
    atomicAdd(bkt + t, s);
    atomicAdd(bkt + 128 + t, q);
  }
}

// ---------------------------------------------------------------- BN finalize
__global__ void bn_finalize(const float* __restrict__ buckets,
                            const float* __restrict__ gamma,
                            const float* __restrict__ beta,
                            float* __restrict__ scaleshift) {
  int t = threadIdx.x;  // 128
  float s = 0.f, q = 0.f;
  for (int j = 0; j < 64; ++j) {
    s += buckets[j * 256 + t];
    q += buckets[j * 256 + 128 + t];
  }
  float mean = s / (float)N_NODES;
  float var = q / (float)N_NODES - mean * mean;
  var = fmaxf(var, 0.f);
  float sc = gamma[t] * rsqrtf(var + BN_EPS);
  scaleshift[t] = sc;
  scaleshift[128 + t] = beta[t] - mean * sc;
}

// ---------------------------------------------------------------- GRU v3 (MFMA)
// 64 rows/block (grid 7813, tail-guarded), 4 waves; wave w: all 64 rows x cols
// w*32..+31. z/r gates: both sides accumulate into ONE acc (sum happens inside
// sigmoid). h gate needs split sides (r * rec_h). h read from Ax LDS (bf16).
__global__ __launch_bounds__(256) void gru_mfma(
    const unsigned short* __restrict__ a_bf, const float* __restrict__ x,
    const unsigned short* __restrict__ pw, const float* __restrict__ gbias,
    const float* __restrict__ scaleshift, float* __restrict__ out) {
  __shared__ unsigned short Aa[64 * 128];  // a_norm bf16, swizzled
  __shared__ unsigned short Ax[64 * 128];  // x bf16, swizzled
  int t = threadIdx.x;
  int r0 = blockIdx.x * 64;

#pragma unroll
  for (int i = 0; i < 4; ++i) {
    int q = t + 256 * i;  // 0..1023 : 64 rows x 16 chunks of 8 feats
    int row = q >> 4, kq = q & 15;
    int gr = r0 + row;
    uint4 av = make_uint4(0, 0, 0, 0);
    float4 x0 = make_float4(0.f, 0.f, 0.f, 0.f), x1 = x0;
    if (gr < N_NODES) {
      size_t g = (size_t)gr * FDIM + kq * 8;
      av = *(const uint4*)(a_bf + g);
      x0 = *(const float4*)(x + g);
      x1 = *(const float4*)(x + g + 4);
    }
    float4 sc0 = *(const float4*)(scaleshift + kq * 8);
    float4 sc1 = *(const float4*)(scaleshift + kq * 8 + 4);
    float4 sh0 = *(const float4*)(scaleshift + 128 + kq * 8);
    float4 sh1 = *(const float4*)(scaleshift + 128 + kq * 8 + 4);
    float a0 = __uint_as_float(av.x << 16), a1 = __uint_as_float(av.x & 0xffff0000u);
    float a2 = __uint_as_float(av.y << 16), a3 = __uint_as_float(av.y & 0xffff0000u);
    float a4 = __uint_as_float(av.z << 16), a5 = __uint_as_float(av.z & 0xffff0000u);
    float a6 = __uint_as_float(av.w << 16), a7 = __uint_as_float(av.w & 0xffff0000u);
    uint4 na = make_uint4(f2bf2(a0 * sc0.x + sh0.x, a1 * sc0.y + sh0.y),
                          f2bf2(a2 * sc0.z + sh0.z, a3 * sc0.w + sh0.w),
                          f2bf2(a4 * sc1.x + sh1.x, a5 * sc1.y + sh1.y),
                          f2bf2(a6 * sc1.z + sh1.z, a7 * sc1.w + sh1.w));
    uint4 nx = make_uint4(f2bf2(x0.x, x0.y), f2bf2(x0.z, x0.w),
                          f2bf2(x1.x, x1.y), f2bf2(x1.z, x1.w));
    int byte = (row * 256 + kq * 16) ^ ((row & 7) << 4);
    *(uint4*)((char*)Aa + byte) = na;
    *(uint4*)((char*)Ax + byte) = nx;
  }
  __syncthreads();

  int w = t >> 6, lane = t & 63;
  int l15 = lane & 15, lg = lane >> 4;

  v4f az[4][2], ar[4][2], ah0[4][2], ah1[4][2];
#pragma unroll
  for (int m = 0; m < 4; ++m)
#pragma unroll
    for (int nb = 0; nb < 2; ++nb) {
      az[m][nb] = (v4f){0.f, 0.f, 0.f, 0.f};
      ar[m][nb] = (v4f){0.f, 0.f, 0.f, 0.f};
      ah0[m][nb] = (v4f){0.f, 0.f, 0.f, 0.f};
      ah1[m][nb] = (v4f){0.f, 0.f, 0.f, 0.f};
    }

#pragma unroll
  for (int ks = 0; ks < 4; ++ks) {
    v8bf aa[4], ax[4];
#pragma unroll
    for (int m = 0; m < 4; ++m) {
      int mm = m * 16 + l15;
      int byte = (mm * 256 + ks * 64 + lg * 16) ^ ((mm & 7) << 4);
      aa[m] = __builtin_bit_cast(v8bf, *(const uint4*)((const char*)Aa + byte));
      ax[m] = __builtin_bit_cast(v8bf, *(const uint4*)((const char*)Ax + byte));
    }
    const unsigned short* wb = pw + w * 24576 + ks * 6144 + lane * 8;
#pragma unroll
    for (int nb = 0; nb < 2; ++nb) {
      const unsigned short* wn = wb + nb * 3072;
      v8bf b0z = __builtin_bit_cast(v8bf, *(const uint4*)(wn));
      v8bf b1z = __builtin_bit_cast(v8bf, *(const uint4*)(wn + 512));
      v8bf b0r = __builtin_bit_cast(v8bf, *(const uint4*)(wn + 1024));
      v8bf b1r = __builtin_bit_cast(v8bf, *(const uint4*)(wn + 1536));
      v8bf b0h = __builtin_bit_cast(v8bf, *(const uint4*)(wn + 2048));
      v8bf b1h = __builtin_bit_cast(v8bf, *(const uint4*)(wn + 2560));
#pragma unroll
      for (int m = 0; m < 4; ++m) {
        az[m][nb] = __builtin_amdgcn_mfma_f32_16x16x32_bf16(aa[m], b0z, az[m][nb], 0, 0, 0);
        az[m][nb] = __builtin_amdgcn_mfma_f32_16x16x32_bf16(ax[m], b1z, az[m][nb], 0, 0, 0);
        ar[m][nb] = __builtin_amdgcn_mfma_f32_16x16x32_bf16(aa[m], b0r, ar[m][nb], 0, 0, 0);
        ar[m][nb] = __builtin_amdgcn_mfma_f32_16x16x32_bf16(ax[m], b1r, ar[m][nb], 0, 0, 0);
        ah0[m][nb] = __builtin_amdgcn_mfma_f32_16x16x32_bf16(aa[m], b0h, ah0[m][nb], 0, 0, 0);
        ah1[m][nb] = __builtin_amdgcn_mfma_f32_16x16x32_bf16(ax[m], b1h, ah1[m][nb], 0, 0, 0);
      }
    }
  }

#pragma unroll
  for (int nb = 0; nb < 2; ++nb) {
    int c = w * 32 + nb * 16 + l15;
    float bz = gbias[c] + gbias[384 + c];
    float br = gbias[128 + c] + gbias[512 + c];
    float bh0 = gbias[256 + c];
    float bh1 = gbias[640 + c];
#pragma unroll
    for (int m = 0; m < 4; ++m) {
#pragma unroll
      for (int r = 0; r < 4; ++r) {
        int rl = m * 16 + 4 * lg + r;
        int row = r0 + rl;
        if (row < N_NODES) {
          float z = fast_sigmoid(az[m][nb][r] + bz);
          float rg = fast_sigmoid(ar[m][nb][r] + br);
          float hc = fast_tanh(ah0[m][nb][r] + bh0 + rg * (ah1[m][nb][r] + bh1));
          int hb = (rl * 256 + c * 2) ^ ((rl & 7) << 4);
          float h = bf2f(*(const unsigned short*)((const char*)Ax + hb));
          __builtin_nontemporal_store(z * h + (1.f - z) * hc,
                                      out + (size_t)row * FDIM + c);
        }
      }
    }
  }
}

// ---------------------------------------------------------------- launch
extern "C" void kernel_launch(void* const* d_in, const int* in_sizes, int n_in,
                              void* d_out, int out_size, void* d_ws, size_t ws_size,
                              hipStream_t stream) {
  const float* x = (const float*)d_in[0];
  const int* pp = (const int*)d_in[1];
  const int* pn = (const int*)d_in[2];
  const float* w_next = (const float*)d_in[3];
  const float* w_prev = (const float*)d_in[4];
  const float* b = (const float*)d_in[5];
  const float* gamma = (const float*)d_in[6];
  const float* beta = (const float*)d_in[7];
  const float* gk = (const float*)d_in[8];
  const float* rk = (const float*)d_in[9];
  const float* gbias = (const float*)d_in[10];
  float* out = (float*)d_out;
  float* ws = (float*)d_ws;

  float* buckets = ws + WS_BUCKETS;
  float* scaleshift = ws + WS_SCALESHIFT;
  unsigned short* pw = (unsigned short*)(ws + WS_PW);
  unsigned short* pw2 = (unsigned short*)(ws + WS_PW2);
  unsigned short* prev_bf = (unsigned short*)(ws + WS_PREV);
  unsigned short* next_bf = prev_bf + (size_t)N_NODES * FDIM;
  unsigned short* a_bf = prev_bf;  // alias: aggre reads rows before overwriting

  unsigned* u = (unsigned*)d_out;
  unsigned* cnt = u + SO_CNT;
  unsigned* off = u + SO_OFF;
  unsigned* part = u + SO_PART;
  unsigned* cur = u + SO_CUR;
  unsigned* srcbuf = u + SO_SRC;
  unsigned short* xbf = (unsigned short*)(u + SO_XBF);  // dead before gru writes out

  hipMemsetAsync(cnt, 0, 2u * N_NODES * sizeof(unsigned), stream);
  hipMemsetAsync(part, 0, 1024 * sizeof(unsigned), stream);
  hipMemsetAsync(buckets, 0, (16384 + 256) * sizeof(float), stream);

  repack_gru<<<384, 256, 0, stream>>>(gk, rk, pw);
  repack_w<<<128, 256, 0, stream>>>(w_next, w_prev, pw2);
  xbf_kernel<<<31250, 256, 0, stream>>>(x, xbf);

  hist_kernel<<<(2 * E_EDGES + 255) / 256, 256, 0, stream>>>(pp, pn, cnt);
  scan1_kernel<<<dim3(489, 2), 256, 0, stream>>>(cnt, off, part);
  scan2_kernel<<<1, 1024, 0, stream>>>(part);
  scan3_kernel<<<dim3((N_NODES + 255) / 256, 2), 256, 0, stream>>>(off, part, cur);
  reorder_kernel<<<(2 * E_EDGES + 255) / 256, 256, 0, stream>>>(pp, pn, cur, srcbuf);
  gather_kernel<<<dim3(N_NODES / 32, 2), 256, 0, stream>>>(xbf, off, srcbuf, prev_bf,
                                                           next_bf);

  aggre_mfma<<<N_NODES / 32, 256, 0, stream>>>(prev_bf, next_bf, xbf, pw2, b, a_bf,
                                               buckets);
  bn_finalize<<<1, 128, 0, stream>>>(buckets, gamma, beta, scaleshift);
  gru_mfma<<<(N_NODES + 63) / 64, 256, 0, stream>>>(a_bf, x, pw, gbias, scaleshift,
                                                    out);
}

// Round 9
// 734.087 us; speedup vs baseline: 1.2162x; 1.2162x over previous
//
#include <hip/hip_runtime.h>
#include <hip/hip_bf16.h>

#define N_NODES 500000
#define E_EDGES 500000
#define FDIM 128
#define BN_EPS 1e-3f
#define OFFS 500001  // per-side stride of the offsets array
#define GCAP 128    // edges staged per chunk in gather

// ws layout (in floats):
//   [0, 16384)        buckets: 64 x (sum[128], sumsq[128])
//   [16384, 16640)    scaleshift: scale[128], shift[128]
//   [16640, 65792)    pw  (gru weights)  bf16 fragment-order, 192 KB
//   [65792, 82176)    pw2 (aggre weights) bf16 fragment-order, 64 KB
//   [82176, ...)      prev_bf [N][128] bf16 (128 MB), then next_bf [N][128] bf16
//   a_bf ALIASES prev_bf (aggre reads its rows to LDS before overwriting them).
#define WS_BUCKETS 0
#define WS_SCALESHIFT 16384
#define WS_PW 16640
#define WS_PW2 65792
#define WS_PREV 82176

// d_out u32 scratch layout (dead once gru_mfma writes d_out at the very end):
//   CNT  at 0         : u32[2][500000]
//   OFF  at 1000000   : u32[2][500001]
//   PART at 2100000   : u32[2][512]
//   CUR  at 2200000   : u32[2][500000]
//   SRC  at 3200000   : u32[2][500000]   (ends at 16.8 MB)
//   XBF  at 6000000   : bf16[N][128]     (24 MB .. 152 MB; read by gather+aggre only)
#define SO_CNT 0
#define SO_OFF 1000000
#define SO_PART 2100000
#define SO_CUR 2200000
#define SO_SRC 3200000
#define SO_XBF 6000000

typedef __attribute__((ext_vector_type(4))) float v4f;
typedef __attribute__((ext_vector_type(8))) __bf16 v8bf;

__device__ __forceinline__ unsigned f2bf_u(float f) {
  unsigned u = __float_as_uint(f);
  return ((u + 0x7FFF + ((u >> 16) & 1)) >> 16) & 0xFFFF;
}
__device__ __forceinline__ unsigned f2bf2(float a, float b) {
  return f2bf_u(a) | (f2bf_u(b) << 16);
}
__device__ __forceinline__ float bf2f(unsigned short u) {
  return __uint_as_float((unsigned)u << 16);
}
__device__ __forceinline__ float fast_sigmoid(float x) {
  float e = __expf(-x);
  return __builtin_amdgcn_rcpf(1.f + e);
}
__device__ __forceinline__ float fast_tanh(float x) {
  x = fminf(fmaxf(x, -15.f), 15.f);
  float e = __expf(2.f * x);
  return (e - 1.f) * __builtin_amdgcn_rcpf(e + 1.f);
}

// ---------------------------------------------------------------- weight repack
__global__ __launch_bounds__(256) void repack_gru(
    const float* __restrict__ gk, const float* __restrict__ rk,
    unsigned short* __restrict__ pw) {
  int idx = blockIdx.x * 256 + threadIdx.x;  // 0..98303
  int side = idx / 49152;
  int rem = idx % 49152;
  int gate = rem >> 14;
  int rr = rem & 16383;
  int c = rr >> 7, k = rr & 127;
  const float* src = side ? rk : gk;
  float v = src[k * 384 + gate * 128 + c];
  int w = c >> 5, nb = (c >> 4) & 1, l15 = c & 15;
  int ks = k >> 5, lg = (k >> 3) & 3, j = k & 7;
  int lane = lg * 16 + l15;
  int e = w * 24576 + ks * 6144 + nb * 3072 + gate * 1024 + side * 512 + lane * 8 + j;
  pw[e] = (unsigned short)f2bf_u(v);
}

__global__ __launch_bounds__(256) void repack_w(
    const float* __restrict__ w_next, const float* __restrict__ w_prev,
    unsigned short* __restrict__ pw2) {
  int idx = blockIdx.x * 256 + threadIdx.x;  // 0..32767
  int side = idx >> 14;
  int rr = idx & 16383;
  int c = rr >> 7, k = rr & 127;
  const float* src = side ? w_prev : w_next;
  float v = src[k * 128 + c];
  int nh = c >> 6, nb = (c >> 4) & 3, l15 = c & 15;
  int ks = k >> 5, lg = (k >> 3) & 3, j = k & 7;
  int lane = lg * 16 + l15;
  int e = nh * 16384 + ks * 4096 + nb * 1024 + side * 512 + lane * 8 + j;
  pw2[e] = (unsigned short)f2bf_u(v);
}

// ---------------------------------------------------------------- x -> bf16
__global__ __launch_bounds__(256) void xbf_kernel(const float* __restrict__ x,
                                                  unsigned short* __restrict__ xbf) {
  size_t i = ((size_t)blockIdx.x * 256 + threadIdx.x) * 8;
  if (i >= (size_t)N_NODES * FDIM) return;
  float4 a = *(const float4*)(x + i);
  float4 b = *(const float4*)(x + i + 4);
  uint4 o = make_uint4(f2bf2(a.x, a.y), f2bf2(a.z, a.w), f2bf2(b.x, b.y),
                       f2bf2(b.z, b.w));
  *(uint4*)(xbf + i) = o;
}

// ---------------------------------------------------------------- CSR build
__global__ __launch_bounds__(256) void hist_kernel(const int* __restrict__ pp,
                                                   const int* __restrict__ pn,
                                                   unsigned* __restrict__ cnt) {
  int i = blockIdx.x * 256 + threadIdx.x;
  if (i >= 2 * E_EDGES) return;
  int side = i >= E_EDGES;
  const int* pair = side ? pn + 2 * (i - E_EDGES) : pp + 2 * i;
  atomicAdd(&cnt[side * N_NODES + pair[0]], 1u);
}

__global__ __launch_bounds__(256) void scan1_kernel(const unsigned* __restrict__ cnt,
                                                    unsigned* __restrict__ off,
                                                    unsigned* __restrict__ part) {
  __shared__ unsigned ls[256];
  int side = blockIdx.y;
  int b = blockIdx.x;
  int td = threadIdx.x;
  int base = b * 1024 + td * 4;
  const unsigned* c = cnt + (size_t)side * N_NODES;
  unsigned v0 = 0, v1 = 0, v2 = 0, v3 = 0;
  if (base + 3 < N_NODES) {
    v0 = c[base]; v1 = c[base + 1]; v2 = c[base + 2]; v3 = c[base + 3];
  } else {
    if (base < N_NODES) v0 = c[base];
    if (base + 1 < N_NODES) v1 = c[base + 1];
    if (base + 2 < N_NODES) v2 = c[base + 2];
  }
  unsigned s = v0 + v1 + v2 + v3;
  ls[td] = s;
  __syncthreads();
  unsigned run = s;
  for (int st = 1; st < 256; st <<= 1) {
    unsigned o = (td >= st) ? ls[td - st] : 0u;
    __syncthreads();
    run += o;
    ls[td] = run;
    __syncthreads();
  }
  unsigned excl = run - s;
  unsigned* oo = off + (size_t)side * OFFS;
  if (base < N_NODES) oo[base] = excl;
  if (base + 1 < N_NODES) oo[base + 1] = excl + v0;
  if (base + 2 < N_NODES) oo[base + 2] = excl + v0 + v1;
  if (base + 3 < N_NODES) oo[base + 3] = excl + v0 + v1 + v2;
  if (td == 255) part[side * 512 + b] = run;
}

__global__ __launch_bounds__(1024) void scan2_kernel(unsigned* __restrict__ part) {
  __shared__ unsigned ls[1024];
  int td = threadIdx.x;
  int b = td & 511;
  unsigned s = part[td];
  ls[td] = s;
  __syncthreads();
  unsigned run = s;
  for (int st = 1; st < 512; st <<= 1) {
    unsigned o = (b >= st) ? ls[td - st] : 0u;
    __syncthreads();
    run += o;
    ls[td] = run;
    __syncthreads();
  }
  part[td] = run - s;
}

__global__ __launch_bounds__(256) void scan3_kernel(unsigned* __restrict__ off,
                                                    const unsigned* __restrict__ part,
                                                    unsigned* __restrict__ cur) {
  int side = blockIdx.y;
  int i = blockIdx.x * 256 + threadIdx.x;
  if (i < N_NODES) {
    unsigned v = off[(size_t)side * OFFS + i] + part[side * 512 + (i >> 10)];
    off[(size_t)side * OFFS + i] = v;
    cur[(size_t)side * N_NODES + i] = v;
  }
  if (i == 0) off[(size_t)side * OFFS + N_NODES] = E_EDGES;
}

__global__ __launch_bounds__(256) void reorder_kernel(const int* __restrict__ pp,
                                                      const int* __restrict__ pn,
                                                      unsigned* __restrict__ cur,
                                                      unsigned* __restrict__ srcbuf) {
  int i = blockIdx.x * 256 + threadIdx.x;
  if (i >= 2 * E_EDGES) return;
  int side = i >= E_EDGES;
  const int* pair = side ? pn + 2 * (i - E_EDGES) : pp + 2 * i;
  unsigned pos = atomicAdd(&cur[(size_t)side * N_NODES + pair[0]], 1u);
  srcbuf[(size_t)side * E_EDGES + pos] = (unsigned)pair[1];
}

// ---------------------------------------------------------------- gather (segment sum)
__global__ __launch_bounds__(256) void gather_kernel(
    const unsigned short* __restrict__ xbf, const unsigned* __restrict__ off,
    const unsigned* __restrict__ srcbuf, unsigned short* __restrict__ prev_bf,
    unsigned short* __restrict__ next_bf) {
  __shared__ unsigned short stage[GCAP][128];  // 32 KB
  __shared__ unsigned soff[33];
  __shared__ unsigned ssrc[GCAP];
  int side = blockIdx.y;
  int r0 = blockIdx.x * 32;
  int t = threadIdx.x;
  const unsigned* oo = off + (size_t)side * OFFS + r0;
  if (t < 33) soff[t] = oo[t];
  __syncthreads();
  unsigned e0 = soff[0], e1 = soff[32];
  const unsigned* sl = srcbuf + (size_t)side * E_EDGES;

  float acc[16];
#pragma unroll
  for (int i = 0; i < 16; ++i) acc[i] = 0.f;
  int rr = t >> 3, fc = t & 7;  // my row, my 16-feature chunk

  for (unsigned base = e0; base < e1; base += GCAP) {
    unsigned cnt = min((unsigned)GCAP, e1 - base);
    if (t < cnt) ssrc[t] = sl[base + t];
    __syncthreads();
    int g = t >> 5, ld = t & 31;
    for (unsigned j = g; j < cnt; j += 8) {
      size_t s = ssrc[j];
      uint2 v = *(const uint2*)(xbf + s * FDIM + ld * 4);
      *(uint2*)&stage[j][ld * 4] = v;
    }
    __syncthreads();
    unsigned rs = soff[rr] > base ? soff[rr] : base;
    unsigned re = soff[rr + 1] < base + GCAP ? soff[rr + 1] : base + GCAP;
    for (unsigned i = rs; i < re; ++i) {
      uint4 u0 = *(const uint4*)&stage[i - base][fc * 16];
      uint4 u1 = *(const uint4*)&stage[i - base][fc * 16 + 8];
      acc[0] += bf2f((unsigned short)(u0.x & 0xffff)); acc[1] += __uint_as_float(u0.x & 0xffff0000u);
      acc[2] += bf2f((unsigned short)(u0.y & 0xffff)); acc[3] += __uint_as_float(u0.y & 0xffff0000u);
      acc[4] += bf2f((unsigned short)(u0.z & 0xffff)); acc[5] += __uint_as_float(u0.z & 0xffff0000u);
      acc[6] += bf2f((unsigned short)(u0.w & 0xffff)); acc[7] += __uint_as_float(u0.w & 0xffff0000u);
      acc[8] += bf2f((unsigned short)(u1.x & 0xffff)); acc[9] += __uint_as_float(u1.x & 0xffff0000u);
      acc[10] += bf2f((unsigned short)(u1.y & 0xffff)); acc[11] += __uint_as_float(u1.y & 0xffff0000u);
      acc[12] += bf2f((unsigned short)(u1.z & 0xffff)); acc[13] += __uint_as_float(u1.z & 0xffff0000u);
      acc[14] += bf2f((unsigned short)(u1.w & 0xffff)); acc[15] += __uint_as_float(u1.w & 0xffff0000u);
    }
    __syncthreads();
  }

  unsigned short* dst = (side ? next_bf : prev_bf) + (size_t)(r0 + rr) * FDIM + fc * 16;
  uint4 o0 = make_uint4(f2bf2(acc[0], acc[1]), f2bf2(acc[2], acc[3]),
                        f2bf2(acc[4], acc[5]), f2bf2(acc[6], acc[7]));
  uint4 o1 = make_uint4(f2bf2(acc[8], acc[9]), f2bf2(acc[10], acc[11]),
                        f2bf2(acc[12], acc[13]), f2bf2(acc[14], acc[15]));
  *(uint4*)dst = o0;
  *(uint4*)(dst + 8) = o1;
}

// ---------------------------------------------------------------- aggre (MFMA) + relu + BN-stats
__global__ __launch_bounds__(256) void aggre_mfma(
    const unsigned short* prev_bf, const unsigned short* __restrict__ next_bf,
    const unsigned short* __restrict__ xbf, const unsigned short* __restrict__ pw2,
    const float* __restrict__ b, unsigned short* a_out,
    float* __restrict__ buckets) {
  __shared__ unsigned short Ap[32 * 128];
  __shared__ unsigned short An[32 * 128];
  __shared__ float rs[2][128];
  __shared__ float rq[2][128];
  int t = threadIdx.x;
  int r0 = blockIdx.x * 32;

#pragma unroll
  for (int i = 0; i < 2; ++i) {
    int q = t + 256 * i;
    int row = q >> 4, kq = q & 15;
    size_t g = (size_t)(r0 + row) * FDIM + kq * 8;
    uint4 pv = *(const uint4*)(prev_bf + g);
    uint4 nv = *(const uint4*)(next_bf + g);
    int byte = (row * 256 + kq * 16) ^ ((row & 7) << 4);
    *(uint4*)((char*)Ap + byte) = pv;
    *(uint4*)((char*)An + byte) = nv;
  }
  __syncthreads();

  int w = t >> 6, lane = t & 63;
  int m0 = (w & 1) * 16, nh = w >> 1;
  int l15 = lane & 15, lg = lane >> 4;

  v4f acc[4];
#pragma unroll
  for (int nb = 0; nb < 4; ++nb) acc[nb] = (v4f){0.f, 0.f, 0.f, 0.f};

#pragma unroll
  for (int ks = 0; ks < 4; ++ks) {
    int mm = m0 + l15;
    int byte = (mm * 256 + ks * 64 + lg * 16) ^ ((mm & 7) << 4);
    v8bf ap = __builtin_bit_cast(v8bf, *(const uint4*)((const char*)Ap + byte));
    v8bf an = __builtin_bit_cast(v8bf, *(const uint4*)((const char*)An + byte));
    const unsigned short* wb = pw2 + nh * 16384 + ks * 4096 + lane * 8;
#pragma unroll
    for (int nb = 0; nb < 4; ++nb) {
      v8bf bn_ = __builtin_bit_cast(v8bf, *(const uint4*)(wb + nb * 1024));
      v8bf bp_ = __builtin_bit_cast(v8bf, *(const uint4*)(wb + nb * 1024 + 512));
      acc[nb] = __builtin_amdgcn_mfma_f32_16x16x32_bf16(an, bn_, acc[nb], 0, 0, 0);
      acc[nb] = __builtin_amdgcn_mfma_f32_16x16x32_bf16(ap, bp_, acc[nb], 0, 0, 0);
    }
  }

  float s1[4], s2[4];
#pragma unroll
  for (int nb = 0; nb < 4; ++nb) {
    int c = nh * 64 + nb * 16 + l15;
    float bb = b[c];
    s1[nb] = 0.f;
    s2[nb] = 0.f;
#pragma unroll
    for (int r = 0; r < 4; ++r) {
      int row = r0 + m0 + 4 * lg + r;
      size_t off = (size_t)row * FDIM + c;
      float v = acc[nb][r] + bb + bf2f(xbf[off]);
      v = fmaxf(v, 0.f);
      a_out[off] = (unsigned short)f2bf_u(v);
      s1[nb] += v;
      s2[nb] += v * v;
    }
    s1[nb] += __shfl_xor(s1[nb], 16);
    s1[nb] += __shfl_xor(s1[nb], 32);
    s2[nb] += __shfl_xor(s2[nb], 16);
    s2[nb] += __shfl_xor(s2[nb], 32);
  }
  if (lane < 16) {
#pragma unroll
    for (int nb = 0; nb < 4; ++nb) {
      rs[w & 1][nh * 64 + nb * 16 + lane] = s1[nb];
      rq[w & 1][nh * 64 + nb * 16 + lane] = s2[nb];
    }
  }
  __syncthreads();
  if (t < 128) {
    float s = rs[0][t] + rs[1][t];
    float q = rq[0][t] + rq[1][t];
    float* bkt = buckets + (size_t)(blockIdx.x & 63) * 256;
    atomicAdd(bkt + t, s);
    atomicAdd(bkt + 128 + t, q);
  }
}

// ---------------------------------------------------------------- BN finalize
__global__ void bn_finalize(const float* __restrict__ buckets,
                            const float* __restrict__ gamma,
                            const float* __restrict__ beta,
                            float* __restrict__ scaleshift) {
  int t = threadIdx.x;  // 128
  float s = 0.f, q = 0.f;
  for (int j = 0; j < 64; ++j) {
    s += buckets[j * 256 + t];
    q += buckets[j * 256 + 128 + t];
  }
  float mean = s / (float)N_NODES;
  float var = q / (float)N_NODES - mean * mean;
  var = fmaxf(var, 0.f);
  float sc = gamma[t] * rsqrtf(var + BN_EPS);
  scaleshift[t] = sc;
  scaleshift[128 + t] = beta[t] - mean * sc;
}

// ---------------------------------------------------------------- GRU v4 (MFMA)
// 32 rows/block (grid 15625), 4 waves; wave w: cols w*32..+31 for all gates.
// z/r: both sides accumulate into ONE acc each (sum happens pre-sigmoid).
// h gate split sides (r * rec_h). h read from Ax LDS (bf16). NT out stores.
__global__ __launch_bounds__(256) void gru_mfma(
    const unsigned short* __restrict__ a_bf, const float* __restrict__ x,
    const unsigned short* __restrict__ pw, const float* __restrict__ gbias,
    const float* __restrict__ scaleshift, float* __restrict__ out) {
  __shared__ unsigned short Aa[32 * 128];  // a_norm bf16, swizzled
  __shared__ unsigned short Ax[32 * 128];  // x bf16, swizzled
  int t = threadIdx.x;
  int r0 = blockIdx.x * 32;

#pragma unroll
  for (int i = 0; i < 2; ++i) {
    int q = t + 256 * i;  // 0..511 : 32 rows x 16 chunks of 8 feats
    int row = q >> 4, kq = q & 15;
    size_t g = (size_t)(r0 + row) * FDIM + kq * 8;
    uint4 av = *(const uint4*)(a_bf + g);
    float4 x0 = *(const float4*)(x + g);
    float4 x1 = *(const float4*)(x + g + 4);
    float4 sc0 = *(const float4*)(scaleshift + kq * 8);
    float4 sc1 = *(const float4*)(scaleshift + kq * 8 + 4);
    float4 sh0 = *(const float4*)(scaleshift + 128 + kq * 8);
    float4 sh1 = *(const float4*)(scaleshift + 128 + kq * 8 + 4);
    float a0 = __uint_as_float(av.x << 16), a1 = __uint_as_float(av.x & 0xffff0000u);
    float a2 = __uint_as_float(av.y << 16), a3 = __uint_as_float(av.y & 0xffff0000u);
    float a4 = __uint_as_float(av.z << 16), a5 = __uint_as_float(av.z & 0xffff0000u);
    float a6 = __uint_as_float(av.w << 16), a7 = __uint_as_float(av.w & 0xffff0000u);
    uint4 na = make_uint4(f2bf2(a0 * sc0.x + sh0.x, a1 * sc0.y + sh0.y),
                          f2bf2(a2 * sc0.z + sh0.z, a3 * sc0.w + sh0.w),
                          f2bf2(a4 * sc1.x + sh1.x, a5 * sc1.y + sh1.y),
                          f2bf2(a6 * sc1.z + sh1.z, a7 * sc1.w + sh1.w));
    uint4 nx = make_uint4(f2bf2(x0.x, x0.y), f2bf2(x0.z, x0.w),
                          f2bf2(x1.x, x1.y), f2bf2(x1.z, x1.w));
    int byte = (row * 256 + kq * 16) ^ ((row & 7) << 4);
    *(uint4*)((char*)Aa + byte) = na;
    *(uint4*)((char*)Ax + byte) = nx;
  }
  __syncthreads();

  int w = t >> 6, lane = t & 63;
  int l15 = lane & 15, lg = lane >> 4;

  v4f az[2][2], ar[2][2], ah0[2][2], ah1[2][2];  // [m][nb]
#pragma unroll
  for (int m = 0; m < 2; ++m)
#pragma unroll
    for (int nb = 0; nb < 2; ++nb) {
      az[m][nb] = (v4f){0.f, 0.f, 0.f, 0.f};
      ar[m][nb] = (v4f){0.f, 0.f, 0.f, 0.f};
      ah0[m][nb] = (v4f){0.f, 0.f, 0.f, 0.f};
      ah1[m][nb] = (v4f){0.f, 0.f, 0.f, 0.f};
    }

#pragma unroll
  for (int ks = 0; ks < 4; ++ks) {
    v8bf aa[2], ax[2];
#pragma unroll
    for (int m = 0; m < 2; ++m) {
      int mm = m * 16 + l15;
      int byte = (mm * 256 + ks * 64 + lg * 16) ^ ((mm & 7) << 4);
      aa[m] = __builtin_bit_cast(v8bf, *(const uint4*)((const char*)Aa + byte));
      ax[m] = __builtin_bit_cast(v8bf, *(const uint4*)((const char*)Ax + byte));
    }
    const unsigned short* wb = pw + w * 24576 + ks * 6144 + lane * 8;
#pragma unroll
    for (int nb = 0; nb < 2; ++nb) {
      const unsigned short* wn = wb + nb * 3072;
      v8bf b0z = __builtin_bit_cast(v8bf, *(const uint4*)(wn));
      v8bf b1z = __builtin_bit_cast(v8bf, *(const uint4*)(wn + 512));
      v8bf b0r = __builtin_bit_cast(v8bf, *(const uint4*)(wn + 1024));
      v8bf b1r = __builtin_bit_cast(v8bf, *(const uint4*)(wn + 1536));
      v8bf b0h = __builtin_bit_cast(v8bf, *(const uint4*)(wn + 2048));
      v8bf b1h = __builtin_bit_cast(v8bf, *(const uint4*)(wn + 2560));
#pragma unroll
      for (int m = 0; m < 2; ++m) {
        az[m][nb] = __builtin_amdgcn_mfma_f32_16x16x32_bf16(aa[m], b0z, az[m][nb], 0, 0, 0);
        az[m][nb] = __builtin_amdgcn_mfma_f32_16x16x32_bf16(ax[m], b1z, az[m][nb], 0, 0, 0);
        ar[m][nb] = __builtin_amdgcn_mfma_f32_16x16x32_bf16(aa[m], b0r, ar[m][nb], 0, 0, 0);
        ar[m][nb] = __builtin_amdgcn_mfma_f32_16x16x32_bf16(ax[m], b1r, ar[m][nb], 0, 0, 0);
        ah0[m][nb] = __builtin_amdgcn_mfma_f32_16x16x32_bf16(aa[m], b0h, ah0[m][nb], 0, 0, 0);
        ah1[m][nb] = __builtin_amdgcn_mfma_f32_16x16x32_bf16(ax[m], b1h, ah1[m][nb], 0, 0, 0);
      }
    }
  }

#pragma unroll
  for (int nb = 0; nb < 2; ++nb) {
    int c = w * 32 + nb * 16 + l15;
    float bz = gbias[c] + gbias[384 + c];
    float br = gbias[128 + c] + gbias[512 + c];
    float bh0 = gbias[256 + c];
    float bh1 = gbias[640 + c];
#pragma unroll
    for (int m = 0; m < 2; ++m) {
#pragma unroll
      for (int r = 0; r < 4; ++r) {
        int rl = m * 16 + 4 * lg + r;
        int row = r0 + rl;
        float z = fast_sigmoid(az[m][nb][r] + bz);
        float rg = fast_sigmoid(ar[m][nb][r] + br);
        float hc = fast_tanh(ah0[m][nb][r] + bh0 + rg * (ah1[m][nb][r] + bh1));
        int hb = (rl * 256 + c * 2) ^ ((rl & 7) << 4);
        float h = bf2f(*(const unsigned short*)((const char*)Ax + hb));
        __builtin_nontemporal_store(z * h + (1.f - z) * hc,
                                    out + (size_t)row * FDIM + c);
      }
    }
  }
}

// ---------------------------------------------------------------- launch
extern "C" void kernel_launch(void* const* d_in, const int* in_sizes, int n_in,
                              void* d_out, int out_size, void* d_ws, size_t ws_size,
                              hipStream_t stream) {
  const float* x = (const float*)d_in[0];
  const int* pp = (const int*)d_in[1];
  const int* pn = (const int*)d_in[2];
  const float* w_next = (const float*)d_in[3];
  const float* w_prev = (const float*)d_in[4];
  const float* b = (const float*)d_in[5];
  const float* gamma = (const float*)d_in[6];
  const float* beta = (const float*)d_in[7];
  const float* gk = (const float*)d_in[8];
  const float* rk = (const float*)d_in[9];
  const float* gbias = (const float*)d_in[10];
  float* out = (float*)d_out;
  float* ws = (float*)d_ws;

  float* buckets = ws + WS_BUCKETS;
  float* scaleshift = ws + WS_SCALESHIFT;
  unsigned short* pw = (unsigned short*)(ws + WS_PW);
  unsigned short* pw2 = (unsigned short*)(ws + WS_PW2);
  unsigned short* prev_bf = (unsigned short*)(ws + WS_PREV);
  unsigned short* next_bf = prev_bf + (size_t)N_NODES * FDIM;
  unsigned short* a_bf = prev_bf;  // alias: aggre reads rows before overwriting

  unsigned* u = (unsigned*)d_out;
  unsigned* cnt = u + SO_CNT;
  unsigned* off = u + SO_OFF;
  unsigned* part = u + SO_PART;
  unsigned* cur = u + SO_CUR;
  unsigned* srcbuf = u + SO_SRC;
  unsigned short* xbf = (unsigned short*)(u + SO_XBF);  // dead before gru writes out

  hipMemsetAsync(cnt, 0, 2u * N_NODES * sizeof(unsigned), stream);
  hipMemsetAsync(part, 0, 1024 * sizeof(unsigned), stream);
  hipMemsetAsync(buckets, 0, (16384 + 256) * sizeof(float), stream);

  repack_gru<<<384, 256, 0, stream>>>(gk, rk, pw);
  repack_w<<<128, 256, 0, stream>>>(w_next, w_prev, pw2);
  xbf_kernel<<<31250, 256, 0, stream>>>(x, xbf);

  hist_kernel<<<(2 * E_EDGES + 255) / 256, 256, 0, stream>>>(pp, pn, cnt);
  scan1_kernel<<<dim3(489, 2), 256, 0, stream>>>(cnt, off, part);
  scan2_kernel<<<1, 1024, 0, stream>>>(part);
  scan3_kernel<<<dim3((N_NODES + 255) / 256, 2), 256, 0, stream>>>(off, part, cur);
  reorder_kernel<<<(2 * E_EDGES + 255) / 256, 256, 0, stream>>>(pp, pn, cur, srcbuf);
  gather_kernel<<<dim3(N_NODES / 32, 2), 256, 0, stream>>>(xbf, off, srcbuf, prev_bf,
                                                           next_bf);

  aggre_mfma<<<N_NODES / 32, 256, 0, stream>>>(prev_bf, next_bf, xbf, pw2, b, a_bf,
                                               buckets);
  bn_finalize<<<1, 128, 0, stream>>>(buckets, gamma, beta, scaleshift);
  gru_mfma<<<N_NODES / 32, 256, 0, stream>>>(a_bf, x, pw, gbias, scaleshift, out);
}

// Round 10
// 552.080 us; speedup vs baseline: 1.6171x; 1.3297x over previous
//
#include <hip/hip_runtime.h>
#include <hip/hip_bf16.h>

#define N_NODES 500000
#define E_EDGES 500000
#define FDIM 128
#define BN_EPS 1e-3f
#define OFFS 500001  // per-side stride of the offsets array
#define GCAP 64      // edges staged per chunk in fused gather

// ws layout (in floats):
//   [0, 16384)        buckets: 64 x (sum[128], sumsq[128])
//   [16384, 16640)    scaleshift: scale[128], shift[128]
//   [16640, 65792)    pw  (gru weights)  bf16 fragment-order, 192 KB
//   [65792, 82176)    pw2 (aggre weights) bf16 fragment-order, 64 KB
//   [82176, +32e6)    xbf  [N][128] bf16 (128 MB)
//   [.., +32e6)       a_bf [N][128] bf16 (128 MB)
//   total 256,328,704 B == previous rounds' footprint exactly.
#define WS_BUCKETS 0
#define WS_SCALESHIFT 16384
#define WS_PW 16640
#define WS_PW2 65792
#define WS_XBF 82176

// d_out u32 scratch layout (CSR only now; dead before gru writes d_out):
#define SO_CNT 0
#define SO_OFF 1000000
#define SO_PART 2100000
#define SO_CUR 2200000
#define SO_SRC 3200000   // ends at 16.8 MB

typedef __attribute__((ext_vector_type(4))) float v4f;
typedef __attribute__((ext_vector_type(8))) __bf16 v8bf;

__device__ __forceinline__ unsigned f2bf_u(float f) {
  unsigned u = __float_as_uint(f);
  return ((u + 0x7FFF + ((u >> 16) & 1)) >> 16) & 0xFFFF;
}
__device__ __forceinline__ unsigned f2bf2(float a, float b) {
  return f2bf_u(a) | (f2bf_u(b) << 16);
}
__device__ __forceinline__ float bf2f(unsigned short u) {
  return __uint_as_float((unsigned)u << 16);
}
__device__ __forceinline__ float fast_sigmoid(float x) {
  float e = __expf(-x);
  return __builtin_amdgcn_rcpf(1.f + e);
}
__device__ __forceinline__ float fast_tanh(float x) {
  x = fminf(fmaxf(x, -15.f), 15.f);
  float e = __expf(2.f * x);
  return (e - 1.f) * __builtin_amdgcn_rcpf(e + 1.f);
}

// ---------------------------------------------------------------- weight repack
__global__ __launch_bounds__(256) void repack_gru(
    const float* __restrict__ gk, const float* __restrict__ rk,
    unsigned short* __restrict__ pw) {
  int idx = blockIdx.x * 256 + threadIdx.x;  // 0..98303
  int side = idx / 49152;
  int rem = idx % 49152;
  int gate = rem >> 14;
  int rr = rem & 16383;
  int c = rr >> 7, k = rr & 127;
  const float* src = side ? rk : gk;
  float v = src[k * 384 + gate * 128 + c];
  int w = c >> 5, nb = (c >> 4) & 1, l15 = c & 15;
  int ks = k >> 5, lg = (k >> 3) & 3, j = k & 7;
  int lane = lg * 16 + l15;
  int e = w * 24576 + ks * 6144 + nb * 3072 + gate * 1024 + side * 512 + lane * 8 + j;
  pw[e] = (unsigned short)f2bf_u(v);
}

__global__ __launch_bounds__(256) void repack_w(
    const float* __restrict__ w_next, const float* __restrict__ w_prev,
    unsigned short* __restrict__ pw2) {
  int idx = blockIdx.x * 256 + threadIdx.x;  // 0..32767
  int side = idx >> 14;
  int rr = idx & 16383;
  int c = rr >> 7, k = rr & 127;
  const float* src = side ? w_prev : w_next;
  float v = src[k * 128 + c];
  int nh = c >> 6, nb = (c >> 4) & 3, l15 = c & 15;
  int ks = k >> 5, lg = (k >> 3) & 3, j = k & 7;
  int lane = lg * 16 + l15;
  int e = nh * 16384 + ks * 4096 + nb * 1024 + side * 512 + lane * 8 + j;
  pw2[e] = (unsigned short)f2bf_u(v);
}

// ---------------------------------------------------------------- x -> bf16
__global__ __launch_bounds__(256) void xbf_kernel(const float* __restrict__ x,
                                                  unsigned short* __restrict__ xbf) {
  size_t i = ((size_t)blockIdx.x * 256 + threadIdx.x) * 8;
  if (i >= (size_t)N_NODES * FDIM) return;
  float4 a = *(const float4*)(x + i);
  float4 b = *(const float4*)(x + i + 4);
  uint4 o = make_uint4(f2bf2(a.x, a.y), f2bf2(a.z, a.w), f2bf2(b.x, b.y),
                       f2bf2(b.z, b.w));
  *(uint4*)(xbf + i) = o;
}

// ---------------------------------------------------------------- CSR build
__global__ __launch_bounds__(256) void hist_kernel(const int* __restrict__ pp,
                                                   const int* __restrict__ pn,
                                                   unsigned* __restrict__ cnt) {
  int i = blockIdx.x * 256 + threadIdx.x;
  if (i >= 2 * E_EDGES) return;
  int side = i >= E_EDGES;
  const int* pair = side ? pn + 2 * (i - E_EDGES) : pp + 2 * i;
  atomicAdd(&cnt[side * N_NODES + pair[0]], 1u);
}

__global__ __launch_bounds__(256) void scan1_kernel(const unsigned* __restrict__ cnt,
                                                    unsigned* __restrict__ off,
                                                    unsigned* __restrict__ part) {
  __shared__ unsigned ls[256];
  int side = blockIdx.y;
  int b = blockIdx.x;
  int td = threadIdx.x;
  int base = b * 1024 + td * 4;
  const unsigned* c = cnt + (size_t)side * N_NODES;
  unsigned v0 = 0, v1 = 0, v2 = 0, v3 = 0;
  if (base + 3 < N_NODES) {
    v0 = c[base]; v1 = c[base + 1]; v2 = c[base + 2]; v3 = c[base + 3];
  } else {
    if (base < N_NODES) v0 = c[base];
    if (base + 1 < N_NODES) v1 = c[base + 1];
    if (base + 2 < N_NODES) v2 = c[base + 2];
  }
  unsigned s = v0 + v1 + v2 + v3;
  ls[td] = s;
  __syncthreads();
  unsigned run = s;
  for (int st = 1; st < 256; st <<= 1) {
    unsigned o = (td >= st) ? ls[td - st] : 0u;
    __syncthreads();
    run += o;
    ls[td] = run;
    __syncthreads();
  }
  unsigned excl = run - s;
  unsigned* oo = off + (size_t)side * OFFS;
  if (base < N_NODES) oo[base] = excl;
  if (base + 1 < N_NODES) oo[base + 1] = excl + v0;
  if (base + 2 < N_NODES) oo[base + 2] = excl + v0 + v1;
  if (base + 3 < N_NODES) oo[base + 3] = excl + v0 + v1 + v2;
  if (td == 255) part[side * 512 + b] = run;
}

__global__ __launch_bounds__(1024) void scan2_kernel(unsigned* __restrict__ part) {
  __shared__ unsigned ls[1024];
  int td = threadIdx.x;
  int b = td & 511;
  unsigned s = part[td];
  ls[td] = s;
  __syncthreads();
  unsigned run = s;
  for (int st = 1; st < 512; st <<= 1) {
    unsigned o = (b >= st) ? ls[td - st] : 0u;
    __syncthreads();
    run += o;
    ls[td] = run;
    __syncthreads();
  }
  part[td] = run - s;
}

__global__ __launch_bounds__(256) void scan3_kernel(unsigned* __restrict__ off,
                                                    const unsigned* __restrict__ part,
                                                    unsigned* __restrict__ cur) {
  int side = blockIdx.y;
  int i = blockIdx.x * 256 + threadIdx.x;
  if (i < N_NODES) {
    unsigned v = off[(size_t)side * OFFS + i] + part[side * 512 + (i >> 10)];
    off[(size_t)side * OFFS + i] = v;
    cur[(size_t)side * N_NODES + i] = v;
  }
  if (i == 0) off[(size_t)side * OFFS + N_NODES] = E_EDGES;
}

__global__ __launch_bounds__(256) void reorder_kernel(const int* __restrict__ pp,
                                                      const int* __restrict__ pn,
                                                      unsigned* __restrict__ cur,
                                                      unsigned* __restrict__ srcbuf) {
  int i = blockIdx.x * 256 + threadIdx.x;
  if (i >= 2 * E_EDGES) return;
  int side = i >= E_EDGES;
  const int* pair = side ? pn + 2 * (i - E_EDGES) : pp + 2 * i;
  unsigned pos = atomicAdd(&cur[(size_t)side * N_NODES + pair[0]], 1u);
  srcbuf[(size_t)side * E_EDGES + pos] = (unsigned)pair[1];
}

// ---------------------------------------------------------------- fused gather + aggre MFMA + relu + BN-stats
// 32 rows/block. Phase 1 (x2 sides): CSR segment-sum of xbf rows -> f32 regs ->
// bf16 swizzled LDS tile (Ap / An). Phase 2: MFMA vs pw2, residual from xbf,
// relu, write a_bf, BN bucket atomics. No prev/next global round trip.
__global__ __launch_bounds__(256) void aggre_fused(
    const unsigned short* __restrict__ xbf, const unsigned* __restrict__ off,
    const unsigned* __restrict__ srcbuf, const unsigned short* __restrict__ pw2,
    const float* __restrict__ b, unsigned short* __restrict__ a_out,
    float* __restrict__ buckets) {
  __shared__ unsigned short Ap[32 * 128];   // 8 KB
  __shared__ unsigned short An[32 * 128];   // 8 KB
  __shared__ unsigned short stage[GCAP][128];  // 16 KB
  __shared__ unsigned soff[33];
  __shared__ unsigned ssrc[GCAP];
  __shared__ float rs[2][128];
  __shared__ float rq[2][128];
  int t = threadIdx.x;
  int r0 = blockIdx.x * 32;
  int rr = t >> 3, fc = t & 7;  // gather role: my row, my 16-feature chunk

  for (int side = 0; side < 2; ++side) {
    const unsigned* oo = off + (size_t)side * OFFS + r0;
    if (t < 33) soff[t] = oo[t];
    __syncthreads();
    unsigned e0 = soff[0], e1 = soff[32];
    const unsigned* sl = srcbuf + (size_t)side * E_EDGES;
    float acc[16];
#pragma unroll
    for (int i = 0; i < 16; ++i) acc[i] = 0.f;

    for (unsigned base = e0; base < e1; base += GCAP) {
      unsigned cnt = (e1 - base) < (unsigned)GCAP ? (e1 - base) : (unsigned)GCAP;
      if (t < cnt) ssrc[t] = sl[base + t];
      __syncthreads();
      int g = t >> 5, ld = t & 31;
      for (unsigned j = g; j < cnt; j += 8) {
        size_t s = ssrc[j];
        uint2 v = *(const uint2*)(xbf + s * FDIM + ld * 4);
        *(uint2*)&stage[j][ld * 4] = v;
      }
      __syncthreads();
      unsigned rsb = soff[rr] > base ? soff[rr] : base;
      unsigned reb = soff[rr + 1] < base + cnt ? soff[rr + 1] : base + cnt;
      for (unsigned i = rsb; i < reb; ++i) {
        uint4 u0 = *(const uint4*)&stage[i - base][fc * 16];
        uint4 u1 = *(const uint4*)&stage[i - base][fc * 16 + 8];
        acc[0] += bf2f((unsigned short)(u0.x & 0xffff)); acc[1] += __uint_as_float(u0.x & 0xffff0000u);
        acc[2] += bf2f((unsigned short)(u0.y & 0xffff)); acc[3] += __uint_as_float(u0.y & 0xffff0000u);
        acc[4] += bf2f((unsigned short)(u0.z & 0xffff)); acc[5] += __uint_as_float(u0.z & 0xffff0000u);
        acc[6] += bf2f((unsigned short)(u0.w & 0xffff)); acc[7] += __uint_as_float(u0.w & 0xffff0000u);
        acc[8] += bf2f((unsigned short)(u1.x & 0xffff)); acc[9] += __uint_as_float(u1.x & 0xffff0000u);
        acc[10] += bf2f((unsigned short)(u1.y & 0xffff)); acc[11] += __uint_as_float(u1.y & 0xffff0000u);
        acc[12] += bf2f((unsigned short)(u1.z & 0xffff)); acc[13] += __uint_as_float(u1.z & 0xffff0000u);
        acc[14] += bf2f((unsigned short)(u1.w & 0xffff)); acc[15] += __uint_as_float(u1.w & 0xffff0000u);
      }
      __syncthreads();
    }
    // acc -> bf16, swizzled write straight into the MFMA A-tile
    unsigned short* dstl = side ? An : Ap;
    int b0 = (rr * 256 + fc * 32) ^ ((rr & 7) << 4);
    int b1 = (rr * 256 + fc * 32 + 16) ^ ((rr & 7) << 4);
    uint4 o0 = make_uint4(f2bf2(acc[0], acc[1]), f2bf2(acc[2], acc[3]),
                          f2bf2(acc[4], acc[5]), f2bf2(acc[6], acc[7]));
    uint4 o1 = make_uint4(f2bf2(acc[8], acc[9]), f2bf2(acc[10], acc[11]),
                          f2bf2(acc[12], acc[13]), f2bf2(acc[14], acc[15]));
    *(uint4*)((char*)dstl + b0) = o0;
    *(uint4*)((char*)dstl + b1) = o1;
    __syncthreads();
  }

  // ---- MFMA phase (identical to previous aggre_mfma) ----
  int w = t >> 6, lane = t & 63;
  int m0 = (w & 1) * 16, nh = w >> 1;
  int l15 = lane & 15, lg = lane >> 4;

  v4f acc[4];
#pragma unroll
  for (int nb = 0; nb < 4; ++nb) acc[nb] = (v4f){0.f, 0.f, 0.f, 0.f};

#pragma unroll
  for (int ks = 0; ks < 4; ++ks) {
    int mm = m0 + l15;
    int byte = (mm * 256 + ks * 64 + lg * 16) ^ ((mm & 7) << 4);
    v8bf ap = __builtin_bit_cast(v8bf, *(const uint4*)((const char*)Ap + byte));
    v8bf an = __builtin_bit_cast(v8bf, *(const uint4*)((const char*)An + byte));
    const unsigned short* wb = pw2 + nh * 16384 + ks * 4096 + lane * 8;
#pragma unroll
    for (int nb = 0; nb < 4; ++nb) {
      v8bf bn_ = __builtin_bit_cast(v8bf, *(const uint4*)(wb + nb * 1024));
      v8bf bp_ = __builtin_bit_cast(v8bf, *(const uint4*)(wb + nb * 1024 + 512));
      acc[nb] = __builtin_amdgcn_mfma_f32_16x16x32_bf16(an, bn_, acc[nb], 0, 0, 0);
      acc[nb] = __builtin_amdgcn_mfma_f32_16x16x32_bf16(ap, bp_, acc[nb], 0, 0, 0);
    }
  }

  float s1[4], s2[4];
#pragma unroll
  for (int nb = 0; nb < 4; ++nb) {
    int c = nh * 64 + nb * 16 + l15;
    float bb = b[c];
    s1[nb] = 0.f;
    s2[nb] = 0.f;
#pragma unroll
    for (int r = 0; r < 4; ++r) {
      int row = r0 + m0 + 4 * lg + r;
      size_t o = (size_t)row * FDIM + c;
      float v = acc[nb][r] + bb + bf2f(xbf[o]);
      v = fmaxf(v, 0.f);
      a_out[o] = (unsigned short)f2bf_u(v);
      s1[nb] += v;
      s2[nb] += v * v;
    }
    s1[nb] += __shfl_xor(s1[nb], 16);
    s1[nb] += __shfl_xor(s1[nb], 32);
    s2[nb] += __shfl_xor(s2[nb], 16);
    s2[nb] += __shfl_xor(s2[nb], 32);
  }
  if (lane < 16) {
#pragma unroll
    for (int nb = 0; nb < 4; ++nb) {
      rs[w & 1][nh * 64 + nb * 16 + lane] = s1[nb];
      rq[w & 1][nh * 64 + nb * 16 + lane] = s2[nb];
    }
  }
  __syncthreads();
  if (t < 128) {
    float s = rs[0][t] + rs[1][t];
    float q = rq[0][t] + rq[1][t];
    float* bkt = buckets + (size_t)(blockIdx.x & 63) * 256;
    atomicAdd(bkt + t, s);
    atomicAdd(bkt + 128 + t, q);
  }
}

// ---------------------------------------------------------------- BN finalize
__global__ void bn_finalize(const float* __restrict__ buckets,
                            const float* __restrict__ gamma,
                            const float* __restrict__ beta,
                            float* __restrict__ scaleshift) {
  int t = threadIdx.x;  // 128
  float s = 0.f, q = 0.f;
  for (int j = 0; j < 64; ++j) {
    s += buckets[j * 256 + t];
    q += buckets[j * 256 + 128 + t];
  }
  float mean = s / (float)N_NODES;
  float var = q / (float)N_NODES - mean * mean;
  var = fmaxf(var, 0.f);
  float sc = gamma[t] * rsqrtf(var + BN_EPS);
  scaleshift[t] = sc;
  scaleshift[128 + t] = beta[t] - mean * sc;
}

// ---------------------------------------------------------------- GRU v5 (MFMA)
// 32 rows/block, 4 waves; wave w: cols w*32..+31. z/r side-fused accumulators.
// x side now read as bf16 from ws xbf (no f32 x read, staging = raw copy).
// h from Ax LDS. NT out stores.
__global__ __launch_bounds__(256) void gru_mfma(
    const unsigned short* __restrict__ a_bf, const unsigned short* __restrict__ xbf,
    const unsigned short* __restrict__ pw, const float* __restrict__ gbias,
    const float* __restrict__ scaleshift, float* __restrict__ out) {
  __shared__ unsigned short Aa[32 * 128];  // a_norm bf16, swizzled
  __shared__ unsigned short Ax[32 * 128];  // x bf16, swizzled
  int t = threadIdx.x;
  int r0 = blockIdx.x * 32;

#pragma unroll
  for (int i = 0; i < 2; ++i) {
    int q = t + 256 * i;  // 0..511 : 32 rows x 16 chunks of 8 feats
    int row = q >> 4, kq = q & 15;
    size_t g = (size_t)(r0 + row) * FDIM + kq * 8;
    uint4 av = *(const uint4*)(a_bf + g);
    uint4 xv = *(const uint4*)(xbf + g);
    float4 sc0 = *(const float4*)(scaleshift + kq * 8);
    float4 sc1 = *(const float4*)(scaleshift + kq * 8 + 4);
    float4 sh0 = *(const float4*)(scaleshift + 128 + kq * 8);
    float4 sh1 = *(const float4*)(scaleshift + 128 + kq * 8 + 4);
    float a0 = __uint_as_float(av.x << 16), a1 = __uint_as_float(av.x & 0xffff0000u);
    float a2 = __uint_as_float(av.y << 16), a3 = __uint_as_float(av.y & 0xffff0000u);
    float a4 = __uint_as_float(av.z << 16), a5 = __uint_as_float(av.z & 0xffff0000u);
    float a6 = __uint_as_float(av.w << 16), a7 = __uint_as_float(av.w & 0xffff0000u);
    uint4 na = make_uint4(f2bf2(a0 * sc0.x + sh0.x, a1 * sc0.y + sh0.y),
                          f2bf2(a2 * sc0.z + sh0.z, a3 * sc0.w + sh0.w),
                          f2bf2(a4 * sc1.x + sh1.x, a5 * sc1.y + sh1.y),
                          f2bf2(a6 * sc1.z + sh1.z, a7 * sc1.w + sh1.w));
    int byte = (row * 256 + kq * 16) ^ ((row & 7) << 4);
    *(uint4*)((char*)Aa + byte) = na;
    *(uint4*)((char*)Ax + byte) = xv;  // raw bf16 copy — no conversion VALU
  }
  __syncthreads();

  int w = t >> 6, lane = t & 63;
  int l15 = lane & 15, lg = lane >> 4;

  v4f az[2][2], ar[2][2], ah0[2][2], ah1[2][2];  // [m][nb]
#pragma unroll
  for (int m = 0; m < 2; ++m)
#pragma unroll
    for (int nb = 0; nb < 2; ++nb) {
      az[m][nb] = (v4f){0.f, 0.f, 0.f, 0.f};
      ar[m][nb] = (v4f){0.f, 0.f, 0.f, 0.f};
      ah0[m][nb] = (v4f){0.f, 0.f, 0.f, 0.f};
      ah1[m][nb] = (v4f){0.f, 0.f, 0.f, 0.f};
    }

#pragma unroll
  for (int ks = 0; ks < 4; ++ks) {
    v8bf aa[2], ax[2];
#pragma unroll
    for (int m = 0; m < 2; ++m) {
      int mm = m * 16 + l15;
      int byte = (mm * 256 + ks * 64 + lg * 16) ^ ((mm & 7) << 4);
      aa[m] = __builtin_bit_cast(v8bf, *(const uint4*)((const char*)Aa + byte));
      ax[m] = __builtin_bit_cast(v8bf, *(const uint4*)((const char*)Ax + byte));
    }
    const unsigned short* wb = pw + w * 24576 + ks * 6144 + lane * 8;
#pragma unroll
    for (int nb = 0; nb < 2; ++nb) {
      const unsigned short* wn = wb + nb * 3072;
      v8bf b0z = __builtin_bit_cast(v8bf, *(const uint4*)(wn));
      v8bf b1z = __builtin_bit_cast(v8bf, *(const uint4*)(wn + 512));
      v8bf b0r = __builtin_bit_cast(v8bf, *(const uint4*)(wn + 1024));
      v8bf b1r = __builtin_bit_cast(v8bf, *(const uint4*)(wn + 1536));
      v8bf b0h = __builtin_bit_cast(v8bf, *(const uint4*)(wn + 2048));
      v8bf b1h = __builtin_bit_cast(v8bf, *(const uint4*)(wn + 2560));
#pragma unroll
      for (int m = 0; m < 2; ++m) {
        az[m][nb] = __builtin_amdgcn_mfma_f32_16x16x32_bf16(aa[m], b0z, az[m][nb], 0, 0, 0);
        az[m][nb] = __builtin_amdgcn_mfma_f32_16x16x32_bf16(ax[m], b1z, az[m][nb], 0, 0, 0);
        ar[m][nb] = __builtin_amdgcn_mfma_f32_16x16x32_bf16(aa[m], b0r, ar[m][nb], 0, 0, 0);
        ar[m][nb] = __builtin_amdgcn_mfma_f32_16x16x32_bf16(ax[m], b1r, ar[m][nb], 0, 0, 0);
        ah0[m][nb] = __builtin_amdgcn_mfma_f32_16x16x32_bf16(aa[m], b0h, ah0[m][nb], 0, 0, 0);
        ah1[m][nb] = __builtin_amdgcn_mfma_f32_16x16x32_bf16(ax[m], b1h, ah1[m][nb], 0, 0, 0);
      }
    }
  }

#pragma unroll
  for (int nb = 0; nb < 2; ++nb) {
    int c = w * 32 + nb * 16 + l15;
    float bz = gbias[c] + gbias[384 + c];
    float br = gbias[128 + c] + gbias[512 + c];
    float bh0 = gbias[256 + c];
    float bh1 = gbias[640 + c];
#pragma unroll
    for (int m = 0; m < 2; ++m) {
#pragma unroll
      for (int r = 0; r < 4; ++r) {
        int rl = m * 16 + 4 * lg + r;
        int row = r0 + rl;
        float z = fast_sigmoid(az[m][nb][r] + bz);
        float rg = fast_sigmoid(ar[m][nb][r] + br);
        float hc = fast_tanh(ah0[m][nb][r] + bh0 + rg * (ah1[m][nb][r] + bh1));
        int hb = (rl * 256 + c * 2) ^ ((rl & 7) << 4);
        float h = bf2f(*(const unsigned short*)((const char*)Ax + hb));
        __builtin_nontemporal_store(z * h + (1.f - z) * hc,
                                    out + (size_t)row * FDIM + c);
      }
    }
  }
}

// ---------------------------------------------------------------- launch
extern "C" void kernel_launch(void* const* d_in, const int* in_sizes, int n_in,
                              void* d_out, int out_size, void* d_ws, size_t ws_size,
                              hipStream_t stream) {
  const float* x = (const float*)d_in[0];
  const int* pp = (const int*)d_in[1];
  const int* pn = (const int*)d_in[2];
  const float* w_next = (const float*)d_in[3];
  const float* w_prev = (const float*)d_in[4];
  const float* b = (const float*)d_in[5];
  const float* gamma = (const float*)d_in[6];
  const float* beta = (const float*)d_in[7];
  const float* gk = (const float*)d_in[8];
  const float* rk = (const float*)d_in[9];
  const float* gbias = (const float*)d_in[10];
  float* out = (float*)d_out;
  float* ws = (float*)d_ws;

  float* buckets = ws + WS_BUCKETS;
  float* scaleshift = ws + WS_SCALESHIFT;
  unsigned short* pw = (unsigned short*)(ws + WS_PW);
  unsigned short* pw2 = (unsigned short*)(ws + WS_PW2);
  unsigned short* xbf = (unsigned short*)(ws + WS_XBF);
  unsigned short* a_bf = xbf + (size_t)N_NODES * FDIM;  // 128 MB after xbf

  unsigned* u = (unsigned*)d_out;  // CSR scratch; dead before gru writes out
  unsigned* cnt = u + SO_CNT;
  unsigned* off = u + SO_OFF;
  unsigned* part = u + SO_PART;
  unsigned* cur = u + SO_CUR;
  unsigned* srcbuf = u + SO_SRC;

  hipMemsetAsync(cnt, 0, 2u * N_NODES * sizeof(unsigned), stream);
  hipMemsetAsync(part, 0, 1024 * sizeof(unsigned), stream);
  hipMemsetAsync(buckets, 0, (16384 + 256) * sizeof(float), stream);

  repack_gru<<<384, 256, 0, stream>>>(gk, rk, pw);
  repack_w<<<128, 256, 0, stream>>>(w_next, w_prev, pw2);
  xbf_kernel<<<31250, 256, 0, stream>>>(x, xbf);

  hist_kernel<<<(2 * E_EDGES + 255) / 256, 256, 0, stream>>>(pp, pn, cnt);
  scan1_kernel<<<dim3(489, 2), 256, 0, stream>>>(cnt, off, part);
  scan2_kernel<<<1, 1024, 0, stream>>>(part);
  scan3_kernel<<<dim3((N_NODES + 255) / 256, 2), 256, 0, stream>>>(off, part, cur);
  reorder_kernel<<<(2 * E_EDGES + 255) / 256, 256, 0, stream>>>(pp, pn, cur, srcbuf);

  aggre_fused<<<N_NODES / 32, 256, 0, stream>>>(xbf, off, srcbuf, pw2, b, a_bf,
                                                buckets);
  bn_finalize<<<1, 128, 0, stream>>>(buckets, gamma, beta, scaleshift);
  gru_mfma<<<N_NODES / 32, 256, 0, stream>>>(a_bf, xbf, pw, gbias, scaleshift, out);
}

// Round 11
// 509.080 us; speedup vs baseline: 1.7537x; 1.0845x over previous
//
#include <hip/hip_runtime.h>
#include <hip/hip_bf16.h>

#define N_NODES 500000
#define E_EDGES 500000
#define FDIM 128
#define BN_EPS 1e-3f
#define OFFS 500001  // per-side stride of the offsets array

// ws layout (in floats):
//   [0, 16384)        buckets: 64 x (sum[128], sumsq[128])
//   [16384, 16640)    scaleshift: scale[128], shift[128]
//   [16640, 65792)    pw  (gru weights)  bf16 fragment-order, 192 KB
//   [65792, 82176)    pw2 (aggre weights) bf16 fragment-order, 64 KB
//   [82176, +32e6)    xbf  [N][128] bf16 (128 MB)
//   [.., +32e6)       a_bf [N][128] bf16 (128 MB)
#define WS_BUCKETS 0
#define WS_SCALESHIFT 16384
#define WS_PW 16640
#define WS_PW2 65792
#define WS_XBF 82176

// d_out u32 scratch layout (CSR only; dead before gru writes d_out):
#define SO_CNT 0
#define SO_OFF 1000000
#define SO_PART 2100000
#define SO_CUR 2200000
#define SO_SRC 3200000   // ends at 16.8 MB

typedef __attribute__((ext_vector_type(4))) float v4f;
typedef __attribute__((ext_vector_type(8))) __bf16 v8bf;

__device__ __forceinline__ unsigned f2bf_u(float f) {
  unsigned u = __float_as_uint(f);
  return ((u + 0x7FFF + ((u >> 16) & 1)) >> 16) & 0xFFFF;
}
__device__ __forceinline__ unsigned f2bf2(float a, float b) {
  return f2bf_u(a) | (f2bf_u(b) << 16);
}
__device__ __forceinline__ float bf2f(unsigned short u) {
  return __uint_as_float((unsigned)u << 16);
}
__device__ __forceinline__ float fast_sigmoid(float x) {
  float e = __expf(-x);
  return __builtin_amdgcn_rcpf(1.f + e);
}
__device__ __forceinline__ float fast_tanh(float x) {
  x = fminf(fmaxf(x, -15.f), 15.f);
  float e = __expf(2.f * x);
  return (e - 1.f) * __builtin_amdgcn_rcpf(e + 1.f);
}

// ---------------------------------------------------------------- weight repack
__global__ __launch_bounds__(256) void repack_gru(
    const float* __restrict__ gk, const float* __restrict__ rk,
    unsigned short* __restrict__ pw) {
  int idx = blockIdx.x * 256 + threadIdx.x;  // 0..98303
  int side = idx / 49152;
  int rem = idx % 49152;
  int gate = rem >> 14;
  int rr = rem & 16383;
  int c = rr >> 7, k = rr & 127;
  const float* src = side ? rk : gk;
  float v = src[k * 384 + gate * 128 + c];
  int w = c >> 5, nb = (c >> 4) & 1, l15 = c & 15;
  int ks = k >> 5, lg = (k >> 3) & 3, j = k & 7;
  int lane = lg * 16 + l15;
  int e = w * 24576 + ks * 6144 + nb * 3072 + gate * 1024 + side * 512 + lane * 8 + j;
  pw[e] = (unsigned short)f2bf_u(v);
}

__global__ __launch_bounds__(256) void repack_w(
    const float* __restrict__ w_next, const float* __restrict__ w_prev,
    unsigned short* __restrict__ pw2) {
  int idx = blockIdx.x * 256 + threadIdx.x;  // 0..32767
  int side = idx >> 14;
  int rr = idx & 16383;
  int c = rr >> 7, k = rr & 127;
  const float* src = side ? w_prev : w_next;
  float v = src[k * 128 + c];
  int nh = c >> 6, nb = (c >> 4) & 3, l15 = c & 15;
  int ks = k >> 5, lg = (k >> 3) & 3, j = k & 7;
  int lane = lg * 16 + l15;
  int e = nh * 16384 + ks * 4096 + nb * 1024 + side * 512 + lane * 8 + j;
  pw2[e] = (unsigned short)f2bf_u(v);
}

// ---------------------------------------------------------------- x -> bf16 (+fused edge histogram)
__global__ __launch_bounds__(256) void xbf_hist_kernel(
    const float* __restrict__ x, unsigned short* __restrict__ xbf,
    const int* __restrict__ pp, const int* __restrict__ pn,
    unsigned* __restrict__ cnt) {
  size_t i = ((size_t)blockIdx.x * 256 + threadIdx.x) * 8;
  if (i < (size_t)N_NODES * FDIM) {
    float4 a = *(const float4*)(x + i);
    float4 b = *(const float4*)(x + i + 4);
    uint4 o = make_uint4(f2bf2(a.x, a.y), f2bf2(a.z, a.w), f2bf2(b.x, b.y),
                         f2bf2(b.z, b.w));
    *(uint4*)(xbf + i) = o;
  }
  int e = blockIdx.x * 256 + threadIdx.x;
  if (e < 2 * E_EDGES) {
    int side = e >= E_EDGES;
    const int* pair = side ? pn + 2 * (e - E_EDGES) : pp + 2 * e;
    atomicAdd(&cnt[side * N_NODES + pair[0]], 1u);
  }
}

// ---------------------------------------------------------------- CSR build
__global__ __launch_bounds__(256) void scan1_kernel(const unsigned* __restrict__ cnt,
                                                    unsigned* __restrict__ off,
                                                    unsigned* __restrict__ part) {
  __shared__ unsigned ls[256];
  int side = blockIdx.y;
  int b = blockIdx.x;
  int td = threadIdx.x;
  int base = b * 1024 + td * 4;
  const unsigned* c = cnt + (size_t)side * N_NODES;
  unsigned v0 = 0, v1 = 0, v2 = 0, v3 = 0;
  if (base + 3 < N_NODES) {
    v0 = c[base]; v1 = c[base + 1]; v2 = c[base + 2]; v3 = c[base + 3];
  } else {
    if (base < N_NODES) v0 = c[base];
    if (base + 1 < N_NODES) v1 = c[base + 1];
    if (base + 2 < N_NODES) v2 = c[base + 2];
  }
  unsigned s = v0 + v1 + v2 + v3;
  ls[td] = s;
  __syncthreads();
  unsigned run = s;
  for (int st = 1; st < 256; st <<= 1) {
    unsigned o = (td >= st) ? ls[td - st] : 0u;
    __syncthreads();
    run += o;
    ls[td] = run;
    __syncthreads();
  }
  unsigned excl = run - s;
  unsigned* oo = off + (size_t)side * OFFS;
  if (base < N_NODES) oo[base] = excl;
  if (base + 1 < N_NODES) oo[base + 1] = excl + v0;
  if (base + 2 < N_NODES) oo[base + 2] = excl + v0 + v1;
  if (base + 3 < N_NODES) oo[base + 3] = excl + v0 + v1 + v2;
  if (td == 255) part[side * 512 + b] = run;
}

__global__ __launch_bounds__(1024) void scan2_kernel(unsigned* __restrict__ part) {
  __shared__ unsigned ls[1024];
  int td = threadIdx.x;
  int b = td & 511;
  unsigned s = part[td];
  ls[td] = s;
  __syncthreads();
  unsigned run = s;
  for (int st = 1; st < 512; st <<= 1) {
    unsigned o = (b >= st) ? ls[td - st] : 0u;
    __syncthreads();
    run += o;
    ls[td] = run;
    __syncthreads();
  }
  part[td] = run - s;
}

__global__ __launch_bounds__(256) void scan3_kernel(unsigned* __restrict__ off,
                                                    const unsigned* __restrict__ part,
                                                    unsigned* __restrict__ cur) {
  int side = blockIdx.y;
  int i = blockIdx.x * 256 + threadIdx.x;
  if (i < N_NODES) {
    unsigned v = off[(size_t)side * OFFS + i] + part[side * 512 + (i >> 10)];
    off[(size_t)side * OFFS + i] = v;
    cur[(size_t)side * N_NODES + i] = v;
  }
  if (i == 0) off[(size_t)side * OFFS + N_NODES] = E_EDGES;
}

__global__ __launch_bounds__(256) void reorder_kernel(const int* __restrict__ pp,
                                                      const int* __restrict__ pn,
                                                      unsigned* __restrict__ cur,
                                                      unsigned* __restrict__ srcbuf) {
  int i = blockIdx.x * 256 + threadIdx.x;
  if (i >= 2 * E_EDGES) return;
  int side = i >= E_EDGES;
  const int* pair = side ? pn + 2 * (i - E_EDGES) : pp + 2 * i;
  unsigned pos = atomicAdd(&cur[(size_t)side * N_NODES + pair[0]], 1u);
  srcbuf[(size_t)side * E_EDGES + pos] = (unsigned)pair[1];
}

// ---------------------------------------------------------------- fused gather + aggre MFMA + relu + BN-stats
// 32 rows/block. Gather: DIRECT global accumulate from L3-resident xbf
// (8 threads/row x 16 feats; 256B/edge coalesced; no stage LDS, 2 barriers).
// Then MFMA vs pw2, residual from xbf, relu, a_bf write, BN bucket atomics.
__global__ __launch_bounds__(256) void aggre_fused(
    const unsigned short* __restrict__ xbf, const unsigned* __restrict__ off,
    const unsigned* __restrict__ srcbuf, const unsigned short* __restrict__ pw2,
    const float* __restrict__ b, unsigned short* __restrict__ a_out,
    float* __restrict__ buckets) {
  __shared__ unsigned short Ap[32 * 128];   // 8 KB
  __shared__ unsigned short An[32 * 128];   // 8 KB
  __shared__ unsigned soff[2][33];
  __shared__ float rs[2][128];
  __shared__ float rq[2][128];
  int t = threadIdx.x;
  int r0 = blockIdx.x * 32;
  int rr = t >> 3, fc = t & 7;  // gather role: my row, my 16-feature chunk

  if (t < 33) soff[0][t] = off[r0 + t];
  if (t >= 64 && t < 97) soff[1][t - 64] = off[(size_t)OFFS + r0 + (t - 64)];
  __syncthreads();

#pragma unroll
  for (int side = 0; side < 2; ++side) {
    unsigned s0 = soff[side][rr], s1 = soff[side][rr + 1];
    const unsigned* sl = srcbuf + (size_t)side * E_EDGES;
    float acc[16];
#pragma unroll
    for (int i = 0; i < 16; ++i) acc[i] = 0.f;

    for (unsigned i = s0; i < s1; ++i) {
      size_t s = sl[i];
      const unsigned short* p = xbf + s * FDIM + fc * 16;
      uint4 u0 = *(const uint4*)p;
      uint4 u1 = *(const uint4*)(p + 8);
      acc[0] += bf2f((unsigned short)(u0.x & 0xffff)); acc[1] += __uint_as_float(u0.x & 0xffff0000u);
      acc[2] += bf2f((unsigned short)(u0.y & 0xffff)); acc[3] += __uint_as_float(u0.y & 0xffff0000u);
      acc[4] += bf2f((unsigned short)(u0.z & 0xffff)); acc[5] += __uint_as_float(u0.z & 0xffff0000u);
      acc[6] += bf2f((unsigned short)(u0.w & 0xffff)); acc[7] += __uint_as_float(u0.w & 0xffff0000u);
      acc[8] += bf2f((unsigned short)(u1.x & 0xffff)); acc[9] += __uint_as_float(u1.x & 0xffff0000u);
      acc[10] += bf2f((unsigned short)(u1.y & 0xffff)); acc[11] += __uint_as_float(u1.y & 0xffff0000u);
      acc[12] += bf2f((unsigned short)(u1.z & 0xffff)); acc[13] += __uint_as_float(u1.z & 0xffff0000u);
      acc[14] += bf2f((unsigned short)(u1.w & 0xffff)); acc[15] += __uint_as_float(u1.w & 0xffff0000u);
    }
    unsigned short* dstl = side ? An : Ap;
    int b0 = (rr * 256 + fc * 32) ^ ((rr & 7) << 4);
    int b1 = (rr * 256 + fc * 32 + 16) ^ ((rr & 7) << 4);
    uint4 o0 = make_uint4(f2bf2(acc[0], acc[1]), f2bf2(acc[2], acc[3]),
                          f2bf2(acc[4], acc[5]), f2bf2(acc[6], acc[7]));
    uint4 o1 = make_uint4(f2bf2(acc[8], acc[9]), f2bf2(acc[10], acc[11]),
                          f2bf2(acc[12], acc[13]), f2bf2(acc[14], acc[15]));
    *(uint4*)((char*)dstl + b0) = o0;
    *(uint4*)((char*)dstl + b1) = o1;
  }
  __syncthreads();

  // ---- MFMA phase ----
  int w = t >> 6, lane = t & 63;
  int m0 = (w & 1) * 16, nh = w >> 1;
  int l15 = lane & 15, lg = lane >> 4;

  v4f acc[4];
#pragma unroll
  for (int nb = 0; nb < 4; ++nb) acc[nb] = (v4f){0.f, 0.f, 0.f, 0.f};

#pragma unroll
  for (int ks = 0; ks < 4; ++ks) {
    int mm = m0 + l15;
    int byte = (mm * 256 + ks * 64 + lg * 16) ^ ((mm & 7) << 4);
    v8bf ap = __builtin_bit_cast(v8bf, *(const uint4*)((const char*)Ap + byte));
    v8bf an = __builtin_bit_cast(v8bf, *(const uint4*)((const char*)An + byte));
    const unsigned short* wb = pw2 + nh * 16384 + ks * 4096 + lane * 8;
#pragma unroll
    for (int nb = 0; nb < 4; ++nb) {
      v8bf bn_ = __builtin_bit_cast(v8bf, *(const uint4*)(wb + nb * 1024));
      v8bf bp_ = __builtin_bit_cast(v8bf, *(const uint4*)(wb + nb * 1024 + 512));
      acc[nb] = __builtin_amdgcn_mfma_f32_16x16x32_bf16(an, bn_, acc[nb], 0, 0, 0);
      acc[nb] = __builtin_amdgcn_mfma_f32_16x16x32_bf16(ap, bp_, acc[nb], 0, 0, 0);
    }
  }

  float s1[4], s2[4];
#pragma unroll
  for (int nb = 0; nb < 4; ++nb) {
    int c = nh * 64 + nb * 16 + l15;
    float bb = b[c];
    s1[nb] = 0.f;
    s2[nb] = 0.f;
#pragma unroll
    for (int r = 0; r < 4; ++r) {
      int row = r0 + m0 + 4 * lg + r;
      size_t o = (size_t)row * FDIM + c;
      float v = acc[nb][r] + bb + bf2f(xbf[o]);
      v = fmaxf(v, 0.f);
      a_out[o] = (unsigned short)f2bf_u(v);
      s1[nb] += v;
      s2[nb] += v * v;
    }
    s1[nb] += __shfl_xor(s1[nb], 16);
    s1[nb] += __shfl_xor(s1[nb], 32);
    s2[nb] += __shfl_xor(s2[nb], 16);
    s2[nb] += __shfl_xor(s2[nb], 32);
  }
  if (lane < 16) {
#pragma unroll
    for (int nb = 0; nb < 4; ++nb) {
      rs[w & 1][nh * 64 + nb * 16 + lane] = s1[nb];
      rq[w & 1][nh * 64 + nb * 16 + lane] = s2[nb];
    }
  }
  __syncthreads();
  if (t < 128) {
    float s = rs[0][t] + rs[1][t];
    float q = rq[0][t] + rq[1][t];
    float* bkt = buckets + (size_t)(blockIdx.x & 63) * 256;
    atomicAdd(bkt + t, s);
    atomicAdd(bkt + 128 + t, q);
  }
}

// ---------------------------------------------------------------- BN finalize
__global__ void bn_finalize(const float* __restrict__ buckets,
                            const float* __restrict__ gamma,
                            const float* __restrict__ beta,
                            float* __restrict__ scaleshift) {
  int t = threadIdx.x;  // 128
  float s = 0.f, q = 0.f;
  for (int j = 0; j < 64; ++j) {
    s += buckets[j * 256 + t];
    q += buckets[j * 256 + 128 + t];
  }
  float mean = s / (float)N_NODES;
  float var = q / (float)N_NODES - mean * mean;
  var = fmaxf(var, 0.f);
  float sc = gamma[t] * rsqrtf(var + BN_EPS);
  scaleshift[t] = sc;
  scaleshift[128 + t] = beta[t] - mean * sc;
}

// ---------------------------------------------------------------- GRU v5 (MFMA)
__global__ __launch_bounds__(256) void gru_mfma(
    const unsigned short* __restrict__ a_bf, const unsigned short* __restrict__ xbf,
    const unsigned short* __restrict__ pw, const float* __restrict__ gbias,
    const float* __restrict__ scaleshift, float* __restrict__ out) {
  __shared__ unsigned short Aa[32 * 128];  // a_norm bf16, swizzled
  __shared__ unsigned short Ax[32 * 128];  // x bf16, swizzled
  int t = threadIdx.x;
  int r0 = blockIdx.x * 32;

#pragma unroll
  for (int i = 0; i < 2; ++i) {
    int q = t + 256 * i;  // 0..511 : 32 rows x 16 chunks of 8 feats
    int row = q >> 4, kq = q & 15;
    size_t g = (size_t)(r0 + row) * FDIM + kq * 8;
    uint4 av = *(const uint4*)(a_bf + g);
    uint4 xv = *(const uint4*)(xbf + g);
    float4 sc0 = *(const float4*)(scaleshift + kq * 8);
    float4 sc1 = *(const float4*)(scaleshift + kq * 8 + 4);
    float4 sh0 = *(const float4*)(scaleshift + 128 + kq * 8);
    float4 sh1 = *(const float4*)(scaleshift + 128 + kq * 8 + 4);
    float a0 = __uint_as_float(av.x << 16), a1 = __uint_as_float(av.x & 0xffff0000u);
    float a2 = __uint_as_float(av.y << 16), a3 = __uint_as_float(av.y & 0xffff0000u);
    float a4 = __uint_as_float(av.z << 16), a5 = __uint_as_float(av.z & 0xffff0000u);
    float a6 = __uint_as_float(av.w << 16), a7 = __uint_as_float(av.w & 0xffff0000u);
    uint4 na = make_uint4(f2bf2(a0 * sc0.x + sh0.x, a1 * sc0.y + sh0.y),
                          f2bf2(a2 * sc0.z + sh0.z, a3 * sc0.w + sh0.w),
                          f2bf2(a4 * sc1.x + sh1.x, a5 * sc1.y + sh1.y),
                          f2bf2(a6 * sc1.z + sh1.z, a7 * sc1.w + sh1.w));
    int byte = (row * 256 + kq * 16) ^ ((row & 7) << 4);
    *(uint4*)((char*)Aa + byte) = na;
    *(uint4*)((char*)Ax + byte) = xv;  // raw bf16 copy — no conversion VALU
  }
  __syncthreads();

  int w = t >> 6, lane = t & 63;
  int l15 = lane & 15, lg = lane >> 4;

  v4f az[2][2], ar[2][2], ah0[2][2], ah1[2][2];  // [m][nb]
#pragma unroll
  for (int m = 0; m < 2; ++m)
#pragma unroll
    for (int nb = 0; nb < 2; ++nb) {
      az[m][nb] = (v4f){0.f, 0.f, 0.f, 0.f};
      ar[m][nb] = (v4f){0.f, 0.f, 0.f, 0.f};
      ah0[m][nb] = (v4f){0.f, 0.f, 0.f, 0.f};
      ah1[m][nb] = (v4f){0.f, 0.f, 0.f, 0.f};
    }

#pragma unroll
  for (int ks = 0; ks < 4; ++ks) {
    v8bf aa[2], ax[2];
#pragma unroll
    for (int m = 0; m < 2; ++m) {
      int mm = m * 16 + l15;
      int byte = (mm * 256 + ks * 64 + lg * 16) ^ ((mm & 7) << 4);
      aa[m] = __builtin_bit_cast(v8bf, *(const uint4*)((const char*)Aa + byte));
      ax[m] = __builtin_bit_cast(v8bf, *(const uint4*)((const char*)Ax + byte));
    }
    const unsigned short* wb = pw + w * 24576 + ks * 6144 + lane * 8;
#pragma unroll
    for (int nb = 0; nb < 2; ++nb) {
      const unsigned short* wn = wb + nb * 3072;
      v8bf b0z = __builtin_bit_cast(v8bf, *(const uint4*)(wn));
      v8bf b1z = __builtin_bit_cast(v8bf, *(const uint4*)(wn + 512));
      v8bf b0r = __builtin_bit_cast(v8bf, *(const uint4*)(wn + 1024));
      v8bf b1r = __builtin_bit_cast(v8bf, *(const uint4*)(wn + 1536));
      v8bf b0h = __builtin_bit_cast(v8bf, *(const uint4*)(wn + 2048));
      v8bf b1h = __builtin_bit_cast(v8bf, *(const uint4*)(wn + 2560));
#pragma unroll
      for (int m = 0; m < 2; ++m) {
        az[m][nb] = __builtin_amdgcn_mfma_f32_16x16x32_bf16(aa[m], b0z, az[m][nb], 0, 0, 0);
        az[m][nb] = __builtin_amdgcn_mfma_f32_16x16x32_bf16(ax[m], b1z, az[m][nb], 0, 0, 0);
        ar[m][nb] = __builtin_amdgcn_mfma_f32_16x16x32_bf16(aa[m], b0r, ar[m][nb], 0, 0, 0);
        ar[m][nb] = __builtin_amdgcn_mfma_f32_16x16x32_bf16(ax[m], b1r, ar[m][nb], 0, 0, 0);
        ah0[m][nb] = __builtin_amdgcn_mfma_f32_16x16x32_bf16(aa[m], b0h, ah0[m][nb], 0, 0, 0);
        ah1[m][nb] = __builtin_amdgcn_mfma_f32_16x16x32_bf16(ax[m], b1h, ah1[m][nb], 0, 0, 0);
      }
    }
  }

#pragma unroll
  for (int nb = 0; nb < 2; ++nb) {
    int c = w * 32 + nb * 16 + l15;
    float bz = gbias[c] + gbias[384 + c];
    float br = gbias[128 + c] + gbias[512 + c];
    float bh0 = gbias[256 + c];
    float bh1 = gbias[640 + c];
#pragma unroll
    for (int m = 0; m < 2; ++m) {
#pragma unroll
      for (int r = 0; r < 4; ++r) {
        int rl = m * 16 + 4 * lg + r;
        int row = r0 + rl;
        float z = fast_sigmoid(az[m][nb][r] + bz);
        float rg = fast_sigmoid(ar[m][nb][r] + br);
        float hc = fast_tanh(ah0[m][nb][r] + bh0 + rg * (ah1[m][nb][r] + bh1));
        int hb = (rl * 256 + c * 2) ^ ((rl & 7) << 4);
        float h = bf2f(*(const unsigned short*)((const char*)Ax + hb));
        __builtin_nontemporal_store(z * h + (1.f - z) * hc,
                                    out + (size_t)row * FDIM + c);
      }
    }
  }
}

// ---------------------------------------------------------------- launch
extern "C" void kernel_launch(void* const* d_in, const int* in_sizes, int n_in,
                              void* d_out, int out_size, void* d_ws, size_t ws_size,
                              hipStream_t stream) {
  const float* x = (const float*)d_in[0];
  const int* pp = (const int*)d_in[1];
  const int* pn = (const int*)d_in[2];
  const float* w_next = (const float*)d_in[3];
  const float* w_prev = (const float*)d_in[4];
  const float* b = (const float*)d_in[5];
  const float* gamma = (const float*)d_in[6];
  const float* beta = (const float*)d_in[7];
  const float* gk = (const float*)d_in[8];
  const float* rk = (const float*)d_in[9];
  const float* gbias = (const float*)d_in[10];
  float* out = (float*)d_out;
  float* ws = (float*)d_ws;

  float* buckets = ws + WS_BUCKETS;
  float* scaleshift = ws + WS_SCALESHIFT;
  unsigned short* pw = (unsigned short*)(ws + WS_PW);
  unsigned short* pw2 = (unsigned short*)(ws + WS_PW2);
  unsigned short* xbf = (unsigned short*)(ws + WS_XBF);
  unsigned short* a_bf = xbf + (size_t)N_NODES * FDIM;  // 128 MB after xbf

  unsigned* u = (unsigned*)d_out;  // CSR scratch; dead before gru writes out
  unsigned* cnt = u + SO_CNT;
  unsigned* off = u + SO_OFF;
  unsigned* part = u + SO_PART;
  unsigned* cur = u + SO_CUR;
  unsigned* srcbuf = u + SO_SRC;

  hipMemsetAsync(cnt, 0, 2u * N_NODES * sizeof(unsigned), stream);
  hipMemsetAsync(part, 0, 1024 * sizeof(unsigned), stream);
  hipMemsetAsync(buckets, 0, (16384 + 256) * sizeof(float), stream);

  repack_gru<<<384, 256, 0, stream>>>(gk, rk, pw);
  repack_w<<<128, 256, 0, stream>>>(w_next, w_prev, pw2);
  xbf_hist_kernel<<<31250, 256, 0, stream>>>(x, xbf, pp, pn, cnt);

  scan1_kernel<<<dim3(489, 2), 256, 0, stream>>>(cnt, off, part);
  scan2_kernel<<<1, 1024, 0, stream>>>(part);
  scan3_kernel<<<dim3((N_NODES + 255) / 256, 2), 256, 0, stream>>>(off, part, cur);
  reorder_kernel<<<(2 * E_EDGES + 255) / 256, 256, 0, stream>>>(pp, pn, cur, srcbuf);

  aggre_fused<<<N_NODES / 32, 256, 0, stream>>>(xbf, off, srcbuf, pw2, b, a_bf,
                                                buckets);
  bn_finalize<<<1, 128, 0, stream>>>(buckets, gamma, beta, scaleshift);
  gru_mfma<<<N_NODES / 32, 256, 0, stream>>>(a_bf, xbf, pw, gbias, scaleshift, out);
}

// Round 12
// 507.418 us; speedup vs baseline: 1.7594x; 1.0033x over previous
//
#include <hip/hip_runtime.h>
#include <hip/hip_bf16.h>

#define N_NODES 500000
#define E_EDGES 500000
#define FDIM 128
#define BN_EPS 1e-3f
#define OFFS 500001  // per-side stride of the offsets array

// ws layout (in floats):
//   [0, 16384)        buckets: 64 x (sum[128], sumsq[128]); after bn_finalize the
//                     first 512 floats are reused as gbias2 (folded GRU biases)
//   [16384, 16640)    scaleshift: scale[128], shift[128]
//   [16640, 65792)    pw  (gru weights)  bf16 fragment-order, 192 KB
//                     side 0 (a-side) is SCALED by BN scale post-bn_finalize
//   [65792, 82176)    pw2 (aggre weights) bf16 fragment-order, 64 KB
//   [82176, +32e6)    xbf  [N][128] bf16 (128 MB)
//   [.., +32e6)       a_bf [N][128] bf16 (128 MB)
#define WS_BUCKETS 0
#define WS_SCALESHIFT 16384
#define WS_PW 16640
#define WS_PW2 65792
#define WS_XBF 82176

// d_out u32 scratch layout (CSR only; dead before gru writes d_out):
#define SO_CNT 0
#define SO_OFF 1000000
#define SO_PART 2100000
#define SO_CUR 2200000
#define SO_SRC 3200000   // ends at 16.8 MB

typedef __attribute__((ext_vector_type(4))) float v4f;
typedef __attribute__((ext_vector_type(8))) __bf16 v8bf;

__device__ __forceinline__ unsigned f2bf_u(float f) {
  unsigned u = __float_as_uint(f);
  return ((u + 0x7FFF + ((u >> 16) & 1)) >> 16) & 0xFFFF;
}
__device__ __forceinline__ unsigned f2bf2(float a, float b) {
  return f2bf_u(a) | (f2bf_u(b) << 16);
}
__device__ __forceinline__ float bf2f(unsigned short u) {
  return __uint_as_float((unsigned)u << 16);
}
__device__ __forceinline__ float fast_sigmoid(float x) {
  float e = __expf(-x);
  return __builtin_amdgcn_rcpf(1.f + e);
}
__device__ __forceinline__ float fast_tanh(float x) {
  x = fminf(fmaxf(x, -15.f), 15.f);
  float e = __expf(2.f * x);
  return (e - 1.f) * __builtin_amdgcn_rcpf(e + 1.f);
}

// ---------------------------------------------------------------- weight repack
// GRU weights, fragment order; a-side (side 0) scaled by BN scale (runs AFTER
// bn_finalize): a_norm @ W == (a .* sc) @ W + sh @ W  (sh@W folded into gbias2).
__global__ __launch_bounds__(256) void repack_gru_scaled(
    const float* __restrict__ gk, const float* __restrict__ rk,
    const float* __restrict__ scaleshift, unsigned short* __restrict__ pw) {
  int idx = blockIdx.x * 256 + threadIdx.x;  // 0..98303
  int side = idx / 49152;
  int rem = idx % 49152;
  int gate = rem >> 14;
  int rr = rem & 16383;
  int c = rr >> 7, k = rr & 127;
  const float* src = side ? rk : gk;
  float v = src[k * 384 + gate * 128 + c];
  if (side == 0) v *= scaleshift[k];
  int w = c >> 5, nb = (c >> 4) & 1, l15 = c & 15;
  int ks = k >> 5, lg = (k >> 3) & 3, j = k & 7;
  int lane = lg * 16 + l15;
  int e = w * 24576 + ks * 6144 + nb * 3072 + gate * 1024 + side * 512 + lane * 8 + j;
  pw[e] = (unsigned short)f2bf_u(v);
}

// Folded GRU bias: gbias2[c]     = gb[c]     + gb[384+c] + (sh@gk)_z[c]
//                  gbias2[128+c] = gb[128+c] + gb[512+c] + (sh@gk)_r[c]
//                  gbias2[256+c] = gb[256+c]             + (sh@gk)_h[c]
//                  gbias2[384+c] = gb[640+c]
__global__ __launch_bounds__(512) void bias_fold(
    const float* __restrict__ gk, const float* __restrict__ gbias,
    const float* __restrict__ scaleshift, float* __restrict__ gbias2) {
  __shared__ float sh[128];
  int j = threadIdx.x;
  if (j < 128) sh[j] = scaleshift[128 + j];
  __syncthreads();
  if (j < 384) {
    float s = 0.f;
#pragma unroll 8
    for (int k = 0; k < 128; ++k) s += sh[k] * gk[k * 384 + j];
    float o = gbias[j] + s;
    if (j < 256) o += gbias[384 + j];
    gbias2[j] = o;
  } else {
    gbias2[j] = gbias[256 + j];  // 640 + (j-384)
  }
}

__global__ __launch_bounds__(256) void repack_w(
    const float* __restrict__ w_next, const float* __restrict__ w_prev,
    unsigned short* __restrict__ pw2) {
  int idx = blockIdx.x * 256 + threadIdx.x;  // 0..32767
  int side = idx >> 14;
  int rr = idx & 16383;
  int c = rr >> 7, k = rr & 127;
  const float* src = side ? w_prev : w_next;
  float v = src[k * 128 + c];
  int nh = c >> 6, nb = (c >> 4) & 3, l15 = c & 15;
  int ks = k >> 5, lg = (k >> 3) & 3, j = k & 7;
  int lane = lg * 16 + l15;
  int e = nh * 16384 + ks * 4096 + nb * 1024 + side * 512 + lane * 8 + j;
  pw2[e] = (unsigned short)f2bf_u(v);
}

// ---------------------------------------------------------------- x -> bf16 (+fused edge histogram)
__global__ __launch_bounds__(256) void xbf_hist_kernel(
    const float* __restrict__ x, unsigned short* __restrict__ xbf,
    const int* __restrict__ pp, const int* __restrict__ pn,
    unsigned* __restrict__ cnt) {
  size_t i = ((size_t)blockIdx.x * 256 + threadIdx.x) * 8;
  if (i < (size_t)N_NODES * FDIM) {
    float4 a = *(const float4*)(x + i);
    float4 b = *(const float4*)(x + i + 4);
    uint4 o = make_uint4(f2bf2(a.x, a.y), f2bf2(a.z, a.w), f2bf2(b.x, b.y),
                         f2bf2(b.z, b.w));
    *(uint4*)(xbf + i) = o;
  }
  int e = blockIdx.x * 256 + threadIdx.x;
  if (e < 2 * E_EDGES) {
    int side = e >= E_EDGES;
    const int* pair = side ? pn + 2 * (e - E_EDGES) : pp + 2 * e;
    atomicAdd(&cnt[side * N_NODES + pair[0]], 1u);
  }
}

// ---------------------------------------------------------------- CSR build
__global__ __launch_bounds__(256) void scan1_kernel(const unsigned* __restrict__ cnt,
                                                    unsigned* __restrict__ off,
                                                    unsigned* __restrict__ part) {
  __shared__ unsigned ls[256];
  int side = blockIdx.y;
  int b = blockIdx.x;
  int td = threadIdx.x;
  int base = b * 1024 + td * 4;
  const unsigned* c = cnt + (size_t)side * N_NODES;
  unsigned v0 = 0, v1 = 0, v2 = 0, v3 = 0;
  if (base + 3 < N_NODES) {
    v0 = c[base]; v1 = c[base + 1]; v2 = c[base + 2]; v3 = c[base + 3];
  } else {
    if (base < N_NODES) v0 = c[base];
    if (base + 1 < N_NODES) v1 = c[base + 1];
    if (base + 2 < N_NODES) v2 = c[base + 2];
  }
  unsigned s = v0 + v1 + v2 + v3;
  ls[td] = s;
  __syncthreads();
  unsigned run = s;
  for (int st = 1; st < 256; st <<= 1) {
    unsigned o = (td >= st) ? ls[td - st] : 0u;
    __syncthreads();
    run += o;
    ls[td] = run;
    __syncthreads();
  }
  unsigned excl = run - s;
  unsigned* oo = off + (size_t)side * OFFS;
  if (base < N_NODES) oo[base] = excl;
  if (base + 1 < N_NODES) oo[base + 1] = excl + v0;
  if (base + 2 < N_NODES) oo[base + 2] = excl + v0 + v1;
  if (base + 3 < N_NODES) oo[base + 3] = excl + v0 + v1 + v2;
  if (td == 255) part[side * 512 + b] = run;
}

__global__ __launch_bounds__(1024) void scan2_kernel(unsigned* __restrict__ part) {
  __shared__ unsigned ls[1024];
  int td = threadIdx.x;
  int b = td & 511;
  unsigned s = part[td];
  ls[td] = s;
  __syncthreads();
  unsigned run = s;
  for (int st = 1; st < 512; st <<= 1) {
    unsigned o = (b >= st) ? ls[td - st] : 0u;
    __syncthreads();
    run += o;
    ls[td] = run;
    __syncthreads();
  }
  part[td] = run - s;
}

__global__ __launch_bounds__(256) void scan3_kernel(unsigned* __restrict__ off,
                                                    const unsigned* __restrict__ part,
                                                    unsigned* __restrict__ cur) {
  int side = blockIdx.y;
  int i = blockIdx.x * 256 + threadIdx.x;
  if (i < N_NODES) {
    unsigned v = off[(size_t)side * OFFS + i] + part[side * 512 + (i >> 10)];
    off[(size_t)side * OFFS + i] = v;
    cur[(size_t)side * N_NODES + i] = v;
  }
  if (i == 0) off[(size_t)side * OFFS + N_NODES] = E_EDGES;
}

__global__ __launch_bounds__(256) void reorder_kernel(const int* __restrict__ pp,
                                                      const int* __restrict__ pn,
                                                      unsigned* __restrict__ cur,
                                                      unsigned* __restrict__ srcbuf) {
  int i = blockIdx.x * 256 + threadIdx.x;
  if (i >= 2 * E_EDGES) return;
  int side = i >= E_EDGES;
  const int* pair = side ? pn + 2 * (i - E_EDGES) : pp + 2 * i;
  unsigned pos = atomicAdd(&cur[(size_t)side * N_NODES + pair[0]], 1u);
  srcbuf[(size_t)side * E_EDGES + pos] = (unsigned)pair[1];
}

// ---------------------------------------------------------------- fused gather + aggre MFMA + relu + BN-stats
__global__ __launch_bounds__(256) void aggre_fused(
    const unsigned short* __restrict__ xbf, const unsigned* __restrict__ off,
    const unsigned* __restrict__ srcbuf, const unsigned short* __restrict__ pw2,
    const float* __restrict__ b, unsigned short* __restrict__ a_out,
    float* __restrict__ buckets) {
  __shared__ unsigned short Ap[32 * 128];   // 8 KB
  __shared__ unsigned short An[32 * 128];   // 8 KB
  __shared__ unsigned soff[2][33];
  __shared__ float rs[2][128];
  __shared__ float rq[2][128];
  int t = threadIdx.x;
  int r0 = blockIdx.x * 32;
  int rr = t >> 3, fc = t & 7;  // gather role: my row, my 16-feature chunk

  if (t < 33) soff[0][t] = off[r0 + t];
  if (t >= 64 && t < 97) soff[1][t - 64] = off[(size_t)OFFS + r0 + (t - 64)];
  __syncthreads();

#pragma unroll
  for (int side = 0; side < 2; ++side) {
    unsigned s0 = soff[side][rr], s1 = soff[side][rr + 1];
    const unsigned* sl = srcbuf + (size_t)side * E_EDGES;
    float acc[16];
#pragma unroll
    for (int i = 0; i < 16; ++i) acc[i] = 0.f;

    for (unsigned i = s0; i < s1; ++i) {
      size_t s = sl[i];
      const unsigned short* p = xbf + s * FDIM + fc * 16;
      uint4 u0 = *(const uint4*)p;
      uint4 u1 = *(const uint4*)(p + 8);
      acc[0] += bf2f((unsigned short)(u0.x & 0xffff)); acc[1] += __uint_as_float(u0.x & 0xffff0000u);
      acc[2] += bf2f((unsigned short)(u0.y & 0xffff)); acc[3] += __uint_as_float(u0.y & 0xffff0000u);
      acc[4] += bf2f((unsigned short)(u0.z & 0xffff)); acc[5] += __uint_as_float(u0.z & 0xffff0000u);
      acc[6] += bf2f((unsigned short)(u0.w & 0xffff)); acc[7] += __uint_as_float(u0.w & 0xffff0000u);
      acc[8] += bf2f((unsigned short)(u1.x & 0xffff)); acc[9] += __uint_as_float(u1.x & 0xffff0000u);
      acc[10] += bf2f((unsigned short)(u1.y & 0xffff)); acc[11] += __uint_as_float(u1.y & 0xffff0000u);
      acc[12] += bf2f((unsigned short)(u1.z & 0xffff)); acc[13] += __uint_as_float(u1.z & 0xffff0000u);
      acc[14] += bf2f((unsigned short)(u1.w & 0xffff)); acc[15] += __uint_as_float(u1.w & 0xffff0000u);
    }
    unsigned short* dstl = side ? An : Ap;
    int b0 = (rr * 256 + fc * 32) ^ ((rr & 7) << 4);
    int b1 = (rr * 256 + fc * 32 + 16) ^ ((rr & 7) << 4);
    uint4 o0 = make_uint4(f2bf2(acc[0], acc[1]), f2bf2(acc[2], acc[3]),
                          f2bf2(acc[4], acc[5]), f2bf2(acc[6], acc[7]));
    uint4 o1 = make_uint4(f2bf2(acc[8], acc[9]), f2bf2(acc[10], acc[11]),
                          f2bf2(acc[12], acc[13]), f2bf2(acc[14], acc[15]));
    *(uint4*)((char*)dstl + b0) = o0;
    *(uint4*)((char*)dstl + b1) = o1;
  }
  __syncthreads();

  // ---- MFMA phase ----
  int w = t >> 6, lane = t & 63;
  int m0 = (w & 1) * 16, nh = w >> 1;
  int l15 = lane & 15, lg = lane >> 4;

  v4f acc[4];
#pragma unroll
  for (int nb = 0; nb < 4; ++nb) acc[nb] = (v4f){0.f, 0.f, 0.f, 0.f};

#pragma unroll
  for (int ks = 0; ks < 4; ++ks) {
    int mm = m0 + l15;
    int byte = (mm * 256 + ks * 64 + lg * 16) ^ ((mm & 7) << 4);
    v8bf ap = __builtin_bit_cast(v8bf, *(const uint4*)((const char*)Ap + byte));
    v8bf an = __builtin_bit_cast(v8bf, *(const uint4*)((const char*)An + byte));
    const unsigned short* wb = pw2 + nh * 16384 + ks * 4096 + lane * 8;
#pragma unroll
    for (int nb = 0; nb < 4; ++nb) {
      v8bf bn_ = __builtin_bit_cast(v8bf, *(const uint4*)(wb + nb * 1024));
      v8bf bp_ = __builtin_bit_cast(v8bf, *(const uint4*)(wb + nb * 1024 + 512));
      acc[nb] = __builtin_amdgcn_mfma_f32_16x16x32_bf16(an, bn_, acc[nb], 0, 0, 0);
      acc[nb] = __builtin_amdgcn_mfma_f32_16x16x32_bf16(ap, bp_, acc[nb], 0, 0, 0);
    }
  }

  float s1[4], s2[4];
#pragma unroll
  for (int nb = 0; nb < 4; ++nb) {
    int c = nh * 64 + nb * 16 + l15;
    float bb = b[c];
    s1[nb] = 0.f;
    s2[nb] = 0.f;
#pragma unroll
    for (int r = 0; r < 4; ++r) {
      int row = r0 + m0 + 4 * lg + r;
      size_t o = (size_t)row * FDIM + c;
      float v = acc[nb][r] + bb + bf2f(xbf[o]);
      v = fmaxf(v, 0.f);
      a_out[o] = (unsigned short)f2bf_u(v);
      s1[nb] += v;
      s2[nb] += v * v;
    }
    s1[nb] += __shfl_xor(s1[nb], 16);
    s1[nb] += __shfl_xor(s1[nb], 32);
    s2[nb] += __shfl_xor(s2[nb], 16);
    s2[nb] += __shfl_xor(s2[nb], 32);
  }
  if (lane < 16) {
#pragma unroll
    for (int nb = 0; nb < 4; ++nb) {
      rs[w & 1][nh * 64 + nb * 16 + lane] = s1[nb];
      rq[w & 1][nh * 64 + nb * 16 + lane] = s2[nb];
    }
  }
  __syncthreads();
  if (t < 128) {
    float s = rs[0][t] + rs[1][t];
    float q = rq[0][t] + rq[1][t];
    float* bkt = buckets + (size_t)(blockIdx.x & 63) * 256;
    atomicAdd(bkt + t, s);
    atomicAdd(bkt + 128 + t, q);
  }
}

// ---------------------------------------------------------------- BN finalize
__global__ void bn_finalize(const float* __restrict__ buckets,
                            const float* __restrict__ gamma,
                            const float* __restrict__ beta,
                            float* __restrict__ scaleshift) {
  int t = threadIdx.x;  // 128
  float s = 0.f, q = 0.f;
  for (int j = 0; j < 64; ++j) {
    s += buckets[j * 256 + t];
    q += buckets[j * 256 + 128 + t];
  }
  float mean = s / (float)N_NODES;
  float var = q / (float)N_NODES - mean * mean;
  var = fmaxf(var, 0.f);
  float sc = gamma[t] * rsqrtf(var + BN_EPS);
  scaleshift[t] = sc;
  scaleshift[128 + t] = beta[t] - mean * sc;
}

// ---------------------------------------------------------------- GRU v6 (MFMA)
// 32 rows/block, 4 waves; wave w: cols w*32..+31. BN scale folded into pw
// side 0; shift@W folded into gbias2 -> staging is PURE raw uint4 copies.
// z/r side-fused accumulators; h from Ax LDS; NT out stores.
__global__ __launch_bounds__(256) void gru_mfma(
    const unsigned short* __restrict__ a_bf, const unsigned short* __restrict__ xbf,
    const unsigned short* __restrict__ pw, const float* __restrict__ gbias2,
    float* __restrict__ out) {
  __shared__ unsigned short Aa[32 * 128];  // raw a bf16, swizzled
  __shared__ unsigned short Ax[32 * 128];  // x bf16, swizzled
  int t = threadIdx.x;
  int r0 = blockIdx.x * 32;

#pragma unroll
  for (int i = 0; i < 2; ++i) {
    int q = t + 256 * i;  // 0..511 : 32 rows x 16 chunks of 8 feats
    int row = q >> 4, kq = q & 15;
    size_t g = (size_t)(r0 + row) * FDIM + kq * 8;
    uint4 av = *(const uint4*)(a_bf + g);
    uint4 xv = *(const uint4*)(xbf + g);
    int byte = (row * 256 + kq * 16) ^ ((row & 7) << 4);
    *(uint4*)((char*)Aa + byte) = av;  // raw copies — zero conversion VALU
    *(uint4*)((char*)Ax + byte) = xv;
  }
  __syncthreads();

  int w = t >> 6, lane = t & 63;
  int l15 = lane & 15, lg = lane >> 4;

  v4f az[2][2], ar[2][2], ah0[2][2], ah1[2][2];  // [m][nb]
#pragma unroll
  for (int m = 0; m < 2; ++m)
#pragma unroll
    for (int nb = 0; nb < 2; ++nb) {
      az[m][nb] = (v4f){0.f, 0.f, 0.f, 0.f};
      ar[m][nb] = (v4f){0.f, 0.f, 0.f, 0.f};
      ah0[m][nb] = (v4f){0.f, 0.f, 0.f, 0.f};
      ah1[m][nb] = (v4f){0.f, 0.f, 0.f, 0.f};
    }

#pragma unroll
  for (int ks = 0; ks < 4; ++ks) {
    v8bf aa[2], ax[2];
#pragma unroll
    for (int m = 0; m < 2; ++m) {
      int mm = m * 16 + l15;
      int byte = (mm * 256 + ks * 64 + lg * 16) ^ ((mm & 7) << 4);
      aa[m] = __builtin_bit_cast(v8bf, *(const uint4*)((const char*)Aa + byte));
      ax[m] = __builtin_bit_cast(v8bf, *(const uint4*)((const char*)Ax + byte));
    }
    const unsigned short* wb = pw + w * 24576 + ks * 6144 + lane * 8;
#pragma unroll
    for (int nb = 0; nb < 2; ++nb) {
      const unsigned short* wn = wb + nb * 3072;
      v8bf b0z = __builtin_bit_cast(v8bf, *(const uint4*)(wn));
      v8bf b1z = __builtin_bit_cast(v8bf, *(const uint4*)(wn + 512));
      v8bf b0r = __builtin_bit_cast(v8bf, *(const uint4*)(wn + 1024));
      v8bf b1r = __builtin_bit_cast(v8bf, *(const uint4*)(wn + 1536));
      v8bf b0h = __builtin_bit_cast(v8bf, *(const uint4*)(wn + 2048));
      v8bf b1h = __builtin_bit_cast(v8bf, *(const uint4*)(wn + 2560));
#pragma unroll
      for (int m = 0; m < 2; ++m) {
        az[m][nb] = __builtin_amdgcn_mfma_f32_16x16x32_bf16(aa[m], b0z, az[m][nb], 0, 0, 0);
        az[m][nb] = __builtin_amdgcn_mfma_f32_16x16x32_bf16(ax[m], b1z, az[m][nb], 0, 0, 0);
        ar[m][nb] = __builtin_amdgcn_mfma_f32_16x16x32_bf16(aa[m], b0r, ar[m][nb], 0, 0, 0);
        ar[m][nb] = __builtin_amdgcn_mfma_f32_16x16x32_bf16(ax[m], b1r, ar[m][nb], 0, 0, 0);
        ah0[m][nb] = __builtin_amdgcn_mfma_f32_16x16x32_bf16(aa[m], b0h, ah0[m][nb], 0, 0, 0);
        ah1[m][nb] = __builtin_amdgcn_mfma_f32_16x16x32_bf16(ax[m], b1h, ah1[m][nb], 0, 0, 0);
      }
    }
  }

#pragma unroll
  for (int nb = 0; nb < 2; ++nb) {
    int c = w * 32 + nb * 16 + l15;
    float bz = gbias2[c];
    float br = gbias2[128 + c];
    float bh0 = gbias2[256 + c];
    float bh1 = gbias2[384 + c];
#pragma unroll
    for (int m = 0; m < 2; ++m) {
#pragma unroll
      for (int r = 0; r < 4; ++r) {
        int rl = m * 16 + 4 * lg + r;
        int row = r0 + rl;
        float z = fast_sigmoid(az[m][nb][r] + bz);
        float rg = fast_sigmoid(ar[m][nb][r] + br);
        float hc = fast_tanh(ah0[m][nb][r] + bh0 + rg * (ah1[m][nb][r] + bh1));
        int hb = (rl * 256 + c * 2) ^ ((rl & 7) << 4);
        float h = bf2f(*(const unsigned short*)((const char*)Ax + hb));
        __builtin_nontemporal_store(z * h + (1.f - z) * hc,
                                    out + (size_t)row * FDIM + c);
      }
    }
  }
}

// ---------------------------------------------------------------- launch
extern "C" void kernel_launch(void* const* d_in, const int* in_sizes, int n_in,
                              void* d_out, int out_size, void* d_ws, size_t ws_size,
                              hipStream_t stream) {
  const float* x = (const float*)d_in[0];
  const int* pp = (const int*)d_in[1];
  const int* pn = (const int*)d_in[2];
  const float* w_next = (const float*)d_in[3];
  const float* w_prev = (const float*)d_in[4];
  const float* b = (const float*)d_in[5];
  const float* gamma = (const float*)d_in[6];
  const float* beta = (const float*)d_in[7];
  const float* gk = (const float*)d_in[8];
  const float* rk = (const float*)d_in[9];
  const float* gbias = (const float*)d_in[10];
  float* out = (float*)d_out;
  float* ws = (float*)d_ws;

  float* buckets = ws + WS_BUCKETS;
  float* gbias2 = ws + WS_BUCKETS;  // reuses buckets after bn_finalize
  float* scaleshift = ws + WS_SCALESHIFT;
  unsigned short* pw = (unsigned short*)(ws + WS_PW);
  unsigned short* pw2 = (unsigned short*)(ws + WS_PW2);
  unsigned short* xbf = (unsigned short*)(ws + WS_XBF);
  unsigned short* a_bf = xbf + (size_t)N_NODES * FDIM;  // 128 MB after xbf

  unsigned* u = (unsigned*)d_out;  // CSR scratch; dead before gru writes out
  unsigned* cnt = u + SO_CNT;
  unsigned* off = u + SO_OFF;
  unsigned* part = u + SO_PART;
  unsigned* cur = u + SO_CUR;
  unsigned* srcbuf = u + SO_SRC;

  hipMemsetAsync(cnt, 0, 2u * N_NODES * sizeof(unsigned), stream);
  hipMemsetAsync(part, 0, 1024 * sizeof(unsigned), stream);
  hipMemsetAsync(buckets, 0, (16384 + 256) * sizeof(float), stream);

  repack_w<<<128, 256, 0, stream>>>(w_next, w_prev, pw2);
  xbf_hist_kernel<<<31250, 256, 0, stream>>>(x, xbf, pp, pn, cnt);

  scan1_kernel<<<dim3(489, 2), 256, 0, stream>>>(cnt, off, part);
  scan2_kernel<<<1, 1024, 0, stream>>>(part);
  scan3_kernel<<<dim3((N_NODES + 255) / 256, 2), 256, 0, stream>>>(off, part, cur);
  reorder_kernel<<<(2 * E_EDGES + 255) / 256, 256, 0, stream>>>(pp, pn, cur, srcbuf);

  aggre_fused<<<N_NODES / 32, 256, 0, stream>>>(xbf, off, srcbuf, pw2, b, a_bf,
                                                buckets);
  bn_finalize<<<1, 128, 0, stream>>>(buckets, gamma, beta, scaleshift);
  // post-BN: fold scale into a-side GRU weights, shift@W into biases
  repack_gru_scaled<<<384, 256, 0, stream>>>(gk, rk, scaleshift, pw);
  bias_fold<<<1, 512, 0, stream>>>(gk, gbias, scaleshift, gbias2);
  gru_mfma<<<N_NODES / 32, 256, 0, stream>>>(a_bf, xbf, pw, gbias2, out);
}